// Round 1
// baseline (2439.066 us; speedup 1.0000x reference)
//
#include <hip/hip_runtime.h>
#include <math.h>

#define BB 8
#define NN 1024
#define KNNK 20
#define LDC 512

// ---------------- squared norms of rows ----------------
__global__ void sqnorm_k(const float* __restrict__ src, int ld, int off, int C,
                         float* __restrict__ sq) {
    int i = blockIdx.x * blockDim.x + threadIdx.x;
    if (i >= BB * NN) return;
    const float* r = src + (size_t)i * ld + off;
    float s = 0.f;
    for (int c = 0; c < C; c++) { float v = r[c]; s += v * v; }
    sq[i] = s;
}

// ---------------- kNN (top-20 of -dist^2, tie -> lower index) ----------------
__global__ __launch_bounds__(256) void knn_k(const float* __restrict__ src, int ld, int off, int C,
                                             const float* __restrict__ sq, int* __restrict__ idxout) {
    __shared__ __align__(16) float ctr[128];
    __shared__ float dist[NN];
    __shared__ float rv[256];
    __shared__ int   ri[256];
    int bn = blockIdx.x;
    int b = bn >> 10;
    int n = bn & (NN - 1);
    int tid = threadIdx.x;
    const float* base = src + (size_t)b * NN * ld + off;
    for (int c = tid; c < C; c += 256) ctr[c] = base[(size_t)n * ld + c];
    __syncthreads();
    float sn = sq[bn];
    if ((C & 3) == 0) {
        int C4 = C >> 2;
        for (int m = tid; m < NN; m += 256) {
            const float4* rm = (const float4*)(base + (size_t)m * ld);
            float d = 0.f;
            for (int c4 = 0; c4 < C4; c4++) {
                float4 a = *(const float4*)&ctr[c4 * 4];
                float4 v = rm[c4];
                d += a.x * v.x + a.y * v.y + a.z * v.z + a.w * v.w;
            }
            dist[m] = 2.f * d - sn - sq[b * NN + m];
        }
    } else {
        for (int m = tid; m < NN; m += 256) {
            const float* rm = base + (size_t)m * ld;
            float d = 0.f;
            for (int c = 0; c < C; c++) d += ctr[c] * rm[c];
            dist[m] = 2.f * d - sn - sq[b * NN + m];
        }
    }
    __syncthreads();
    for (int t = 0; t < KNNK; t++) {
        float bv = -INFINITY; int bi = NN;
        for (int m = tid; m < NN; m += 256) {
            float v = dist[m];
            if (v > bv) { bv = v; bi = m; }   // ascending m: keeps lowest index on tie
        }
        rv[tid] = bv; ri[tid] = bi;
        __syncthreads();
        for (int s = 128; s > 0; s >>= 1) {
            if (tid < s) {
                float ov = rv[tid + s]; int oi = ri[tid + s];
                if (ov > rv[tid] || (ov == rv[tid] && oi < ri[tid])) { rv[tid] = ov; ri[tid] = oi; }
            }
            __syncthreads();
        }
        if (tid == 0) { idxout[bn * KNNK + t] = ri[0]; dist[ri[0]] = -INFINITY; }
        __syncthreads();
    }
}

// ---------------- edge conv: y = Wa@neigh + (Wb-Wa)@ctr ; stats + max/min over k ----------------
template<int C, int O>
__global__ __launch_bounds__(O) void edgeconv_k(const float* __restrict__ xt, int ld, int off_in,
                                                const int* __restrict__ idx, const float* __restrict__ w,
                                                float* __restrict__ ymax, float* __restrict__ ymin,
                                                float* __restrict__ psum, float* __restrict__ psumsq) {
    __shared__ __align__(16) float ctr[C];
    __shared__ __align__(16) float neigh[KNNK][C];
    __shared__ int nb[KNNK];
    int bn = blockIdx.x;
    int b = bn >> 10;
    int n = bn & (NN - 1);
    int tid = threadIdx.x;
    if (tid < KNNK) nb[tid] = idx[bn * KNNK + tid];
    __syncthreads();
    const float* base = xt + (size_t)b * NN * ld + off_in;
    for (int c = tid; c < C; c += O) ctr[c] = base[(size_t)n * ld + c];
    for (int j = tid; j < KNNK * C; j += O) {
        int k = j / C, c = j - k * C;
        neigh[k][c] = base[(size_t)nb[k] * ld + c];
    }
    __syncthreads();
    int o = tid;
    const float* wrow = w + (size_t)o * 2 * C;
    float t0 = 0.f;
    for (int c = 0; c < C; c++) t0 += (wrow[C + c] - wrow[c]) * ctr[c];
    float acc[KNNK];
#pragma unroll
    for (int k = 0; k < KNNK; k++) acc[k] = t0;
    if constexpr ((C & 3) == 0) {
        for (int c4 = 0; c4 < C / 4; c4++) {
            float4 wv = *(const float4*)&wrow[c4 * 4];
#pragma unroll
            for (int k = 0; k < KNNK; k++) {
                float4 nv = *(const float4*)&neigh[k][c4 * 4];
                acc[k] += wv.x * nv.x + wv.y * nv.y + wv.z * nv.z + wv.w * nv.w;
            }
        }
    } else {
        for (int c = 0; c < C; c++) {
            float wv = wrow[c];
#pragma unroll
            for (int k = 0; k < KNNK; k++) acc[k] += wv * neigh[k][c];
        }
    }
    float mx = -INFINITY, mn = INFINITY, s = 0.f, ss = 0.f;
#pragma unroll
    for (int k = 0; k < KNNK; k++) {
        float v = acc[k];
        mx = fmaxf(mx, v); mn = fminf(mn, v);
        s += v; ss += v * v;
    }
    ymax[(size_t)bn * O + o] = mx;
    ymin[(size_t)bn * O + o] = mn;
    psum  [(size_t)o * (BB * NN) + bn] = s;
    psumsq[(size_t)o * (BB * NN) + bn] = ss;
}

// ---------------- BN stats from per-block partials ----------------
__global__ __launch_bounds__(256) void bnstats_k(const float* __restrict__ psum, const float* __restrict__ psumsq,
                                                 const float* __restrict__ g, const float* __restrict__ beta,
                                                 double invM, float* __restrict__ s_out, float* __restrict__ t_out) {
    __shared__ double rs[256], rss[256];
    int o = blockIdx.x, tid = threadIdx.x;
    double s = 0, ss = 0;
    for (int i = tid; i < BB * NN; i += 256) {
        s  += psum  [(size_t)o * (BB * NN) + i];
        ss += psumsq[(size_t)o * (BB * NN) + i];
    }
    rs[tid] = s; rss[tid] = ss;
    __syncthreads();
    for (int st = 128; st > 0; st >>= 1) {
        if (tid < st) { rs[tid] += rs[tid + st]; rss[tid] += rss[tid + st]; }
        __syncthreads();
    }
    if (tid == 0) {
        double mean = rs[0] * invM;
        double var  = rss[0] * invM - mean * mean;
        float inv = (float)(1.0 / sqrt(var + 1e-5));
        float sc = g[o] * inv;
        s_out[o] = sc;
        t_out[o] = beta[o] - (float)mean * sc;
    }
}

// ---------------- apply BN + lrelu to max/min (monotone trick), write into cat buffer ----------------
template<int O>
__global__ void epilogue_k(const float* __restrict__ ymax, const float* __restrict__ ymin,
                           const float* __restrict__ s, const float* __restrict__ t,
                           float* __restrict__ xtcat, int off_out) {
    int i = blockIdx.x * blockDim.x + threadIdx.x;
    if (i >= BB * NN * O) return;
    int bn = i / O;
    int o = i & (O - 1);
    float sc = s[o];
    float v = sc >= 0.f ? ymax[i] : ymin[i];
    float y = sc * v + t[o];
    y = y >= 0.f ? y : 0.2f * y;
    xtcat[(size_t)bn * LDC + off_out + o] = y;
}

// ---------------- stage 5: y5 = w5 @ cat (per 16-row tile) ----------------
__global__ __launch_bounds__(256) void gemm5_k(const float* __restrict__ xtcat, const float* __restrict__ w5,
                                               float* __restrict__ y5) {
    __shared__ __align__(16) float rows[16][512];
    int bn0 = blockIdx.x * 16;
    int tid = threadIdx.x;
    for (int j = tid; j < 16 * 512; j += 256) ((float*)rows)[j] = xtcat[(size_t)bn0 * 512 + j];
    __syncthreads();
    for (int o = tid; o < 512; o += 256) {
        const float4* wr = (const float4*)(w5 + (size_t)o * 512);
        float acc[16];
#pragma unroll
        for (int i = 0; i < 16; i++) acc[i] = 0.f;
        for (int c4 = 0; c4 < 128; c4++) {
            float4 wv = wr[c4];
#pragma unroll
            for (int i = 0; i < 16; i++) {
                float4 rv = *(const float4*)&rows[i][c4 * 4];
                acc[i] += wv.x * rv.x + wv.y * rv.y + wv.z * rv.z + wv.w * rv.w;
            }
        }
#pragma unroll
        for (int i = 0; i < 16; i++) y5[(size_t)(bn0 + i) * 512 + o] = acc[i];
    }
}

// ---------------- stage 5 BN stats straight from y5 ----------------
__global__ __launch_bounds__(256) void bnstats5_k(const float* __restrict__ y5, const float* __restrict__ g,
                                                  const float* __restrict__ beta,
                                                  float* __restrict__ s_out, float* __restrict__ t_out) {
    __shared__ double rs[256], rss[256];
    int o = blockIdx.x, tid = threadIdx.x;
    double s = 0, ss = 0;
    for (int i = tid; i < BB * NN; i += 256) {
        float v = y5[(size_t)i * 512 + o];
        s += v; ss += (double)v * v;
    }
    rs[tid] = s; rss[tid] = ss;
    __syncthreads();
    for (int st = 128; st > 0; st >>= 1) {
        if (tid < st) { rs[tid] += rs[tid + st]; rss[tid] += rss[tid + st]; }
        __syncthreads();
    }
    if (tid == 0) {
        double invM = 1.0 / (BB * NN);
        double mean = rs[0] * invM;
        double var  = rss[0] * invM - mean * mean;
        float inv = (float)(1.0 / sqrt(var + 1e-5));
        float sc = g[o] * inv;
        s_out[o] = sc;
        t_out[o] = beta[o] - (float)mean * sc;
    }
}

// ---------------- BN+lrelu+max over N, then feat @ wemb^T ----------------
__global__ __launch_bounds__(256) void final_k(const float* __restrict__ y5, const float* __restrict__ s,
                                               const float* __restrict__ t, const float* __restrict__ wemb,
                                               float* __restrict__ out) {
    __shared__ __align__(16) float feat[512];
    int b = blockIdx.x, tid = threadIdx.x;
    for (int o = tid; o < 512; o += 256) {
        float sc = s[o], tt = t[o];
        float m = -INFINITY;
        for (int n = 0; n < NN; n++) {
            float v = sc * y5[(size_t)(b * NN + n) * 512 + o] + tt;
            v = v >= 0.f ? v : 0.2f * v;
            m = fmaxf(m, v);
        }
        feat[o] = m;
    }
    __syncthreads();
    const float4* wr = (const float4*)(wemb + (size_t)tid * 512);
    float acc = 0.f;
    for (int c4 = 0; c4 < 128; c4++) {
        float4 wv = wr[c4];
        float4 fv = *(const float4*)&feat[c4 * 4];
        acc += wv.x * fv.x + wv.y * fv.y + wv.z * fv.z + wv.w * fv.w;
    }
    out[(size_t)b * 256 + tid] = acc;
}

extern "C" void kernel_launch(void* const* d_in, const int* in_sizes, int n_in,
                              void* d_out, int out_size, void* d_ws, size_t ws_size,
                              hipStream_t stream) {
    const float* x    = (const float*)d_in[0];
    const float* w1   = (const float*)d_in[1];
    const float* g1   = (const float*)d_in[2];
    const float* b1   = (const float*)d_in[3];
    const float* w2   = (const float*)d_in[4];
    const float* g2   = (const float*)d_in[5];
    const float* b2   = (const float*)d_in[6];
    const float* w3   = (const float*)d_in[7];
    const float* g3   = (const float*)d_in[8];
    const float* b3   = (const float*)d_in[9];
    const float* w4   = (const float*)d_in[10];
    const float* g4   = (const float*)d_in[11];
    const float* b4   = (const float*)d_in[12];
    const float* w5   = (const float*)d_in[13];
    const float* g5   = (const float*)d_in[14];
    const float* b5   = (const float*)d_in[15];
    const float* wemb = (const float*)d_in[16];
    float* out = (float*)d_out;

    float* fws    = (float*)d_ws;
    float* xtcat  = fws;                        // 8*1024*512          = 4,194,304
    float* ymax   = xtcat + (size_t)BB * NN * 512;       // 8*1024*256 = 2,097,152
    float* ymin   = ymax + (size_t)BB * NN * 256;        //              2,097,152
    float* y5     = ymax;                       // alias (ymax+ymin = 4,194,304 floats)
    float* psum   = ymin + (size_t)BB * NN * 256;        // 256*8192   = 2,097,152
    float* psumsq = psum + (size_t)256 * BB * NN;        //              2,097,152
    float* sqn    = psumsq + (size_t)256 * BB * NN;      // 8192
    float* s_arr  = sqn + BB * NN;              // 512
    float* t_arr  = s_arr + 512;                // 512
    int*   idxb   = (int*)(t_arr + 512);        // 8192*20 ints

    const double invM_edge = 1.0 / ((double)BB * NN * KNNK);
    const int nbn = BB * NN;

    // ---- Stage 1: in = x (B,N,3), out channels [0,64) ----
    sqnorm_k<<<(nbn + 255) / 256, 256, 0, stream>>>(x, 3, 0, 3, sqn);
    knn_k<<<nbn, 256, 0, stream>>>(x, 3, 0, 3, sqn, idxb);
    edgeconv_k<3, 64><<<nbn, 64, 0, stream>>>(x, 3, 0, idxb, w1, ymax, ymin, psum, psumsq);
    bnstats_k<<<64, 256, 0, stream>>>(psum, psumsq, g1, b1, invM_edge, s_arr, t_arr);
    epilogue_k<64><<<(nbn * 64 + 255) / 256, 256, 0, stream>>>(ymax, ymin, s_arr, t_arr, xtcat, 0);

    // ---- Stage 2: in ch [0,64), out [64,128) ----
    sqnorm_k<<<(nbn + 255) / 256, 256, 0, stream>>>(xtcat, 512, 0, 64, sqn);
    knn_k<<<nbn, 256, 0, stream>>>(xtcat, 512, 0, 64, sqn, idxb);
    edgeconv_k<64, 64><<<nbn, 64, 0, stream>>>(xtcat, 512, 0, idxb, w2, ymax, ymin, psum, psumsq);
    bnstats_k<<<64, 256, 0, stream>>>(psum, psumsq, g2, b2, invM_edge, s_arr, t_arr);
    epilogue_k<64><<<(nbn * 64 + 255) / 256, 256, 0, stream>>>(ymax, ymin, s_arr, t_arr, xtcat, 64);

    // ---- Stage 3: in ch [64,128), out [128,256) ----
    sqnorm_k<<<(nbn + 255) / 256, 256, 0, stream>>>(xtcat, 512, 64, 64, sqn);
    knn_k<<<nbn, 256, 0, stream>>>(xtcat, 512, 64, 64, sqn, idxb);
    edgeconv_k<64, 128><<<nbn, 128, 0, stream>>>(xtcat, 512, 64, idxb, w3, ymax, ymin, psum, psumsq);
    bnstats_k<<<128, 256, 0, stream>>>(psum, psumsq, g3, b3, invM_edge, s_arr, t_arr);
    epilogue_k<128><<<(nbn * 128 + 255) / 256, 256, 0, stream>>>(ymax, ymin, s_arr, t_arr, xtcat, 128);

    // ---- Stage 4: in ch [128,256), out [256,512) ----
    sqnorm_k<<<(nbn + 255) / 256, 256, 0, stream>>>(xtcat, 512, 128, 128, sqn);
    knn_k<<<nbn, 256, 0, stream>>>(xtcat, 512, 128, 128, sqn, idxb);
    edgeconv_k<128, 256><<<nbn, 256, 0, stream>>>(xtcat, 512, 128, idxb, w4, ymax, ymin, psum, psumsq);
    bnstats_k<<<256, 256, 0, stream>>>(psum, psumsq, g4, b4, invM_edge, s_arr, t_arr);
    epilogue_k<256><<<(nbn * 256 + 255) / 256, 256, 0, stream>>>(ymax, ymin, s_arr, t_arr, xtcat, 256);

    // ---- Stage 5: y5 = w5 @ cat, BN over (B,N), lrelu, max over N, @ wemb^T ----
    gemm5_k<<<nbn / 16, 256, 0, stream>>>(xtcat, w5, y5);
    bnstats5_k<<<512, 256, 0, stream>>>(y5, g5, b5, s_arr, t_arr);
    final_k<<<BB, 256, 0, stream>>>(y5, s_arr, t_arr, wemb, out);
}

// Round 2
// 1669.141 us; speedup vs baseline: 1.4613x; 1.4613x over previous
//
#include <hip/hip_runtime.h>
#include <hip/hip_bf16.h>
#include <math.h>

#define BB 8
#define NN 1024
#define KNNK 20
#define LDC 512

typedef __attribute__((ext_vector_type(8))) short bfrag8;
typedef __attribute__((ext_vector_type(4))) float facc4;

struct bh4 { __hip_bfloat16 x, y, z, w; };
__device__ inline void st_bf4(__hip_bfloat16* p, float a, float b, float c, float d) {
    bh4 t; t.x = __float2bfloat16(a); t.y = __float2bfloat16(b);
    t.z = __float2bfloat16(c); t.w = __float2bfloat16(d);
    *(bh4*)p = t;
}

// ---------------- squared norms of rows ----------------
__global__ void sqnorm_k(const float* __restrict__ src, int ld, int off, int C,
                         float* __restrict__ sq) {
    int i = blockIdx.x * blockDim.x + threadIdx.x;
    if (i >= BB * NN) return;
    const float* r = src + (size_t)i * ld + off;
    float s = 0.f;
    for (int c = 0; c < C; c++) { float v = r[c]; s += v * v; }
    sq[i] = s;
}

// ---------------- stage-1 distances (C=3) ----------------
// rank key: 2*dot(q,c) - |c|^2   (dropping -|q|^2: per-query constant, order-preserving)
__global__ void dist3_k(const float* __restrict__ x, const float* __restrict__ sq,
                        float* __restrict__ dist) {
    int q = blockIdx.x;
    int b = q >> 10;
    int cand = blockIdx.y * 256 + threadIdx.x;
    float qx = x[q * 3 + 0], qy = x[q * 3 + 1], qz = x[q * 3 + 2];
    const float* cr = x + (size_t)(b * NN + cand) * 3;
    float d = qx * cr[0] + qy * cr[1] + qz * cr[2];
    dist[(size_t)q * NN + cand] = 2.f * d - sq[b * NN + cand];
}

// ---------------- stages 2-4 distances: GEMM-style, ld=512 ----------------
// grid: 8 batches x 16 cand-tiles x 8 q-splits = 1024 blocks, 256 thr (4 waves)
template<int C>
__global__ __launch_bounds__(256) void dist_k(const float* __restrict__ xt, int off,
                                              const float* __restrict__ sq,
                                              float* __restrict__ dist) {
    int b    = blockIdx.x >> 7;
    int tile = (blockIdx.x >> 3) & 15;
    int qs   = blockIdx.x & 7;
    int lane = threadIdx.x & 63;
    int wv   = __builtin_amdgcn_readfirstlane(threadIdx.x >> 6);
    int cand = tile * 64 + lane;
    // candidate row in registers
    float4 row[C / 4];
    const float* rp = xt + (size_t)(b * NN + cand) * LDC + off;
#pragma unroll
    for (int i = 0; i < C / 4; i++) row[i] = *(const float4*)(rp + 4 * i);
    float sqc = sq[b * NN + cand];
    // 2 q-groups per wave (8 per qs-split, strided by 4 waves)
    for (int qg = qs * 8 + wv; qg < qs * 8 + 8; qg += 4) {
        int q0 = qg * 16;
        float acc[16];
#pragma unroll
        for (int i = 0; i < 16; i++) acc[i] = 0.f;
        const float* qbase = xt + (size_t)(b * NN + q0) * LDC + off;
#pragma unroll 2
        for (int c4 = 0; c4 < C / 4; c4++) {
            float4 rv = row[c4];
#pragma unroll
            for (int i = 0; i < 16; i++) {
                float4 qv = *(const float4*)(qbase + (size_t)i * LDC + 4 * c4);
                acc[i] += rv.x * qv.x + rv.y * qv.y + rv.z * qv.z + rv.w * qv.w;
            }
        }
#pragma unroll
        for (int i = 0; i < 16; i++)
            dist[(size_t)(b * NN + q0 + i) * NN + cand] = 2.f * acc[i] - sqc;
    }
}

// ---------------- top-20 selection: one wave per query, no barriers ----------------
__global__ __launch_bounds__(256) void select_k(const float* __restrict__ dist,
                                                int* __restrict__ idxout) {
    int q = blockIdx.x * 4 + (threadIdx.x >> 6);
    int lane = threadIdx.x & 63;
    const float* dq = dist + (size_t)q * NN;
    float d[16];
#pragma unroll
    for (int j = 0; j < 16; j++) d[j] = dq[lane + 64 * j];
    for (int t = 0; t < KNNK; t++) {
        float bv = d[0]; int bj = 0;
#pragma unroll
        for (int j = 1; j < 16; j++) if (d[j] > bv) { bv = d[j]; bj = j; }
        int bm = bj * 64 + lane;
        for (int s = 1; s < 64; s <<= 1) {
            float ov = __shfl_xor(bv, s);
            int   om = __shfl_xor(bm, s);
            if (ov > bv || (ov == bv && om < bm)) { bv = ov; bm = om; }
        }
        if (lane == 0) idxout[q * KNNK + t] = bm;
        if ((bm & 63) == lane) {
            int slot = bm >> 6;
#pragma unroll
            for (int j = 0; j < 16; j++) if (j == slot) d[j] = -INFINITY;
        }
    }
}

// ---------------- stage-1 edge conv (C=3, tiny) ----------------
template<int C, int O>
__global__ __launch_bounds__(O) void edgeconv_k(const float* __restrict__ xt, int ld, int off_in,
                                                const int* __restrict__ idx, const float* __restrict__ w,
                                                float* __restrict__ ymax, float* __restrict__ ymin,
                                                float* __restrict__ psum, float* __restrict__ psumsq) {
    __shared__ __align__(16) float ctr[C];
    __shared__ __align__(16) float neigh[KNNK][C];
    __shared__ int nb[KNNK];
    int bn = blockIdx.x;
    int b = bn >> 10;
    int n = bn & (NN - 1);
    int tid = threadIdx.x;
    if (tid < KNNK) nb[tid] = idx[bn * KNNK + tid];
    __syncthreads();
    const float* base = xt + (size_t)b * NN * ld + off_in;
    for (int c = tid; c < C; c += O) ctr[c] = base[(size_t)n * ld + c];
    for (int j = tid; j < KNNK * C; j += O) {
        int k = j / C, c = j - k * C;
        neigh[k][c] = base[(size_t)nb[k] * ld + c];
    }
    __syncthreads();
    int o = tid;
    const float* wrow = w + (size_t)o * 2 * C;
    float t0 = 0.f;
    for (int c = 0; c < C; c++) t0 += (wrow[C + c] - wrow[c]) * ctr[c];
    float acc[KNNK];
#pragma unroll
    for (int k = 0; k < KNNK; k++) acc[k] = t0;
    for (int c = 0; c < C; c++) {
        float wv = wrow[c];
#pragma unroll
        for (int k = 0; k < KNNK; k++) acc[k] += wv * neigh[k][c];
    }
    float mx = -INFINITY, mn = INFINITY, s = 0.f, ss = 0.f;
#pragma unroll
    for (int k = 0; k < KNNK; k++) {
        float v = acc[k];
        mx = fmaxf(mx, v); mn = fminf(mn, v);
        s += v; ss += v * v;
    }
    ymax[(size_t)bn * O + o] = mx;
    ymin[(size_t)bn * O + o] = mn;
    psum  [(size_t)o * (BB * NN) + bn] = s;
    psumsq[(size_t)o * (BB * NN) + bn] = ss;
}

// ---------------- stages 2-3 edge conv fp32, o/k register blocking ----------------
// block 256 = 4 waves, wave = 1 point; lane: og=lane&15 (16 o-groups), kg=lane>>4 (4 kgrps x 5 k)
template<int C, int O>
__global__ __launch_bounds__(256) void edgeconv_f32(const float* __restrict__ xt, int off_in,
                                                    const int* __restrict__ idx, const float* __restrict__ w,
                                                    float* __restrict__ ymax, float* __restrict__ ymin,
                                                    float* __restrict__ psum, float* __restrict__ psumsq) {
    constexpr int OB = O / 16;
    __shared__ float neigh[4][KNNK][C + 4];
    __shared__ float ctr[4][C];
    __shared__ int nb[4 * KNNK];
    int bn0 = blockIdx.x * 4;
    int b = bn0 >> 10;
    int tid = threadIdx.x;
    if (tid < 4 * KNNK) nb[tid] = idx[bn0 * KNNK + tid];
    __syncthreads();
    const float* xb = xt + (size_t)b * NN * LDC + off_in;
    for (int j = tid; j < 4 * (C / 4); j += 256) {
        int p = j / (C / 4), c4 = j % (C / 4);
        *(float4*)&ctr[p][4 * c4] = *(const float4*)(xb + (size_t)((bn0 & (NN - 1)) + p) * LDC + 4 * c4);
    }
    for (int j = tid; j < 4 * KNNK * (C / 4); j += 256) {
        int p = j / (KNNK * C / 4);
        int r = j % (KNNK * C / 4);
        int k = r / (C / 4), c4 = r % (C / 4);
        *(float4*)&neigh[p][k][4 * c4] = *(const float4*)(xb + (size_t)nb[p * KNNK + k] * LDC + 4 * c4);
    }
    __syncthreads();
    int lane = tid & 63, wv = tid >> 6;
    int bn = bn0 + wv;
    int og = lane & 15, kg = lane >> 4;
    // ctr term t0 per owned o
    float t0[OB];
#pragma unroll
    for (int jo = 0; jo < OB; jo++) t0[jo] = 0.f;
    for (int c4 = 0; c4 < C / 4; c4++) {
        float4 cv = *(const float4*)&ctr[wv][4 * c4];
#pragma unroll
        for (int jo = 0; jo < OB; jo++) {
            const float* wr = w + (size_t)(og + 16 * jo) * 2 * C;
            float4 wav = *(const float4*)(wr + 4 * c4);
            float4 wbv = *(const float4*)(wr + C + 4 * c4);
            t0[jo] += (wbv.x - wav.x) * cv.x + (wbv.y - wav.y) * cv.y
                    + (wbv.z - wav.z) * cv.z + (wbv.w - wav.w) * cv.w;
        }
    }
    float acc[OB][5];
#pragma unroll
    for (int jo = 0; jo < OB; jo++)
#pragma unroll
        for (int j = 0; j < 5; j++) acc[jo][j] = t0[jo];
    for (int c4 = 0; c4 < C / 4; c4++) {
        float4 wl[OB];
#pragma unroll
        for (int jo = 0; jo < OB; jo++)
            wl[jo] = *(const float4*)(w + (size_t)(og + 16 * jo) * 2 * C + 4 * c4);
#pragma unroll
        for (int j = 0; j < 5; j++) {
            float4 nv = *(const float4*)&neigh[wv][kg * 5 + j][4 * c4];
#pragma unroll
            for (int jo = 0; jo < OB; jo++)
                acc[jo][j] += wl[jo].x * nv.x + wl[jo].y * nv.y + wl[jo].z * nv.z + wl[jo].w * nv.w;
        }
    }
#pragma unroll
    for (int jo = 0; jo < OB; jo++) {
        float mx = -INFINITY, mn = INFINITY, s = 0.f, ss = 0.f;
#pragma unroll
        for (int j = 0; j < 5; j++) {
            float v = acc[jo][j];
            mx = fmaxf(mx, v); mn = fminf(mn, v);
            s += v; ss += v * v;
        }
        for (int m = 16; m < 64; m <<= 1) {
            mx = fmaxf(mx, __shfl_xor(mx, m));
            mn = fminf(mn, __shfl_xor(mn, m));
            s += __shfl_xor(s, m);
            ss += __shfl_xor(ss, m);
        }
        if (kg == 0) {
            int o = og + 16 * jo;
            ymax[(size_t)bn * O + o] = mx;
            ymin[(size_t)bn * O + o] = mn;
            psum  [(size_t)o * (BB * NN) + bn] = s;
            psumsq[(size_t)o * (BB * NN) + bn] = ss;
        }
    }
}

// ---------------- stage-4 edge conv: bf16 MFMA, fused stats ----------------
// grid = ceil(8192/6)*2 halves; block 256 = 4 waves (2x2), tile M=128(6pts x 20 + pad) x N=128, K=256
#define S4_PTS 6
__global__ __launch_bounds__(256) void edgeconv4_mfma(const float* __restrict__ xt,
                                                      const int* __restrict__ idx,
                                                      const float* __restrict__ w4,
                                                      float* __restrict__ ymax, float* __restrict__ ymin,
                                                      float* __restrict__ psum, float* __restrict__ psumsq) {
    __shared__ union ShU {
        struct { __hip_bfloat16 A[128][72]; __hip_bfloat16 W[128][72]; } s;
        __hip_bfloat16 Y[128][136];
    } sh;
    __shared__ float ctr[S4_PTS][128];
    __shared__ int nidx[S4_PTS * KNNK];
    int blk = blockIdx.x >> 1, h = blockIdx.x & 1;
    int p0 = blk * S4_PTS;
    int npts = 8192 - p0 < S4_PTS ? 8192 - p0 : S4_PTS;
    int tid = threadIdx.x;
    for (int j = tid; j < npts * KNNK; j += 256) nidx[j] = idx[p0 * KNNK + j];
    for (int j = tid; j < npts * 32; j += 256) {
        int p = j >> 5, c4 = j & 31;
        *(float4*)&ctr[p][4 * c4] = *(const float4*)(xt + (size_t)(p0 + p) * LDC + 128 + 4 * c4);
    }
    facc4 acc[4][4];
    facc4 zz = {0.f, 0.f, 0.f, 0.f};
#pragma unroll
    for (int mi = 0; mi < 4; mi++)
#pragma unroll
        for (int ni = 0; ni < 4; ni++) acc[mi][ni] = zz;
    int lane = tid & 63;
    int wvx = tid >> 6;
    int mw = wvx >> 1, nw = wvx & 1;
    int m0 = lane & 15, qd = lane >> 4;
    int r  = tid & 127, hf = tid >> 7;   // staging row / col-half
    __syncthreads();
    for (int kc = 0; kc < 4; kc++) {
        // ---- stage A (edge matrix) and W half ----
        if (r < npts * KNNK) {
            int p = r / KNNK;
            int src = nidx[r];
            int gsrc = ((p0 + p) >> 10) * NN + src;
            if (kc < 2) {
                const float* nrow = xt + (size_t)gsrc * LDC + 128 + 64 * kc + 32 * hf;
                const float* crow = &ctr[p][64 * kc + 32 * hf];
#pragma unroll
                for (int u2 = 0; u2 < 8; u2++) {
                    float4 nv = *(const float4*)(nrow + 4 * u2);
                    float4 cv = *(const float4*)(crow + 4 * u2);
                    st_bf4(&sh.s.A[r][32 * hf + 4 * u2], nv.x - cv.x, nv.y - cv.y, nv.z - cv.z, nv.w - cv.w);
                }
            } else {
                const float* crow = &ctr[p][64 * (kc - 2) + 32 * hf];
#pragma unroll
                for (int u2 = 0; u2 < 8; u2++) {
                    float4 cv = *(const float4*)(crow + 4 * u2);
                    st_bf4(&sh.s.A[r][32 * hf + 4 * u2], cv.x, cv.y, cv.z, cv.w);
                }
            }
        } else {
#pragma unroll
            for (int u2 = 0; u2 < 8; u2++)
                st_bf4(&sh.s.A[r][32 * hf + 4 * u2], 0.f, 0.f, 0.f, 0.f);
        }
        {
            const float* wrow = w4 + (size_t)(128 * h + r) * 256 + 64 * kc + 32 * hf;
#pragma unroll
            for (int u2 = 0; u2 < 8; u2++) {
                float4 wv = *(const float4*)(wrow + 4 * u2);
                st_bf4(&sh.s.W[r][32 * hf + 4 * u2], wv.x, wv.y, wv.z, wv.w);
            }
        }
        __syncthreads();
        // ---- MFMA on this K-chunk ----
#pragma unroll
        for (int kk = 0; kk < 2; kk++) {
            bfrag8 af[4], bf[4];
#pragma unroll
            for (int mi = 0; mi < 4; mi++)
                af[mi] = *(const bfrag8*)&sh.s.A[64 * mw + 16 * mi + m0][32 * kk + 8 * qd];
#pragma unroll
            for (int ni = 0; ni < 4; ni++)
                bf[ni] = *(const bfrag8*)&sh.s.W[64 * nw + 16 * ni + m0][32 * kk + 8 * qd];
#pragma unroll
            for (int mi = 0; mi < 4; mi++)
#pragma unroll
                for (int ni = 0; ni < 4; ni++)
                    acc[mi][ni] = __builtin_amdgcn_mfma_f32_16x16x32_bf16(af[mi], bf[ni], acc[mi][ni], 0, 0, 0);
        }
        __syncthreads();
    }
    // ---- write y tile to LDS (bf16), C/D layout: col=lane&15, row=quad*4+reg ----
#pragma unroll
    for (int mi = 0; mi < 4; mi++)
#pragma unroll
        for (int ni = 0; ni < 4; ni++)
#pragma unroll
            for (int rg = 0; rg < 4; rg++) {
                int R = 64 * mw + 16 * mi + 4 * qd + rg;
                int Cc = 64 * nw + 16 * ni + m0;
                sh.Y[R][Cc] = __float2bfloat16(acc[mi][ni][rg]);
            }
    __syncthreads();
    // ---- fused stats: max/min/sum/sumsq over k per (point, channel) ----
    for (int it = tid; it < S4_PTS * 128; it += 256) {
        int p = it >> 7, col = it & 127;
        if (p >= npts) continue;
        float mx = -INFINITY, mn = INFINITY, s = 0.f, ss = 0.f;
#pragma unroll
        for (int kn = 0; kn < KNNK; kn++) {
            float v = __bfloat162float(sh.Y[KNNK * p + kn][col]);
            mx = fmaxf(mx, v); mn = fminf(mn, v);
            s += v; ss += v * v;
        }
        int bn = p0 + p;
        int o = 128 * h + col;
        ymax[(size_t)bn * 256 + o] = mx;
        ymin[(size_t)bn * 256 + o] = mn;
        psum  [(size_t)o * (BB * NN) + bn] = s;
        psumsq[(size_t)o * (BB * NN) + bn] = ss;
    }
}

// ---------------- BN stats from per-point partials ----------------
__global__ __launch_bounds__(256) void bnstats_k(const float* __restrict__ psum, const float* __restrict__ psumsq,
                                                 const float* __restrict__ g, const float* __restrict__ beta,
                                                 double invM, float* __restrict__ s_out, float* __restrict__ t_out) {
    __shared__ double rs[256], rss[256];
    int o = blockIdx.x, tid = threadIdx.x;
    double s = 0, ss = 0;
    for (int i = tid; i < BB * NN; i += 256) {
        s  += psum  [(size_t)o * (BB * NN) + i];
        ss += psumsq[(size_t)o * (BB * NN) + i];
    }
    rs[tid] = s; rss[tid] = ss;
    __syncthreads();
    for (int st = 128; st > 0; st >>= 1) {
        if (tid < st) { rs[tid] += rs[tid + st]; rss[tid] += rss[tid + st]; }
        __syncthreads();
    }
    if (tid == 0) {
        double mean = rs[0] * invM;
        double var  = rss[0] * invM - mean * mean;
        float inv = (float)(1.0 / sqrt(var + 1e-5));
        float sc = g[o] * inv;
        s_out[o] = sc;
        t_out[o] = beta[o] - (float)mean * sc;
    }
}

// ---------------- BN+lrelu on max/min (monotone), write into cat buffer ----------------
template<int O>
__global__ void epilogue_k(const float* __restrict__ ymax, const float* __restrict__ ymin,
                           const float* __restrict__ s, const float* __restrict__ t,
                           float* __restrict__ xtcat, int off_out) {
    int i = blockIdx.x * blockDim.x + threadIdx.x;
    if (i >= BB * NN * O) return;
    int bn = i / O;
    int o = i & (O - 1);
    float sc = s[o];
    float v = sc >= 0.f ? ymax[i] : ymin[i];
    float y = sc * v + t[o];
    y = y >= 0.f ? y : 0.2f * y;
    xtcat[(size_t)bn * LDC + off_out + o] = y;
}

// ---------------- stage 5: y5 = w5 @ cat ----------------
__global__ __launch_bounds__(256) void gemm5_k(const float* __restrict__ xtcat, const float* __restrict__ w5,
                                               float* __restrict__ y5) {
    __shared__ __align__(16) float rows[16][512];
    int bn0 = blockIdx.x * 16;
    int tid = threadIdx.x;
    for (int j = tid; j < 16 * 512; j += 256) ((float*)rows)[j] = xtcat[(size_t)bn0 * 512 + j];
    __syncthreads();
    for (int o = tid; o < 512; o += 256) {
        const float4* wr = (const float4*)(w5 + (size_t)o * 512);
        float acc[16];
#pragma unroll
        for (int i = 0; i < 16; i++) acc[i] = 0.f;
        for (int c4 = 0; c4 < 128; c4++) {
            float4 wv = wr[c4];
#pragma unroll
            for (int i = 0; i < 16; i++) {
                float4 rv = *(const float4*)&rows[i][c4 * 4];
                acc[i] += wv.x * rv.x + wv.y * rv.y + wv.z * rv.z + wv.w * rv.w;
            }
        }
#pragma unroll
        for (int i = 0; i < 16; i++) y5[(size_t)(bn0 + i) * 512 + o] = acc[i];
    }
}

// ---------------- stage 5 BN stats ----------------
__global__ __launch_bounds__(256) void bnstats5_k(const float* __restrict__ y5, const float* __restrict__ g,
                                                  const float* __restrict__ beta,
                                                  float* __restrict__ s_out, float* __restrict__ t_out) {
    __shared__ double rs[256], rss[256];
    int o = blockIdx.x, tid = threadIdx.x;
    double s = 0, ss = 0;
    for (int i = tid; i < BB * NN; i += 256) {
        float v = y5[(size_t)i * 512 + o];
        s += v; ss += (double)v * v;
    }
    rs[tid] = s; rss[tid] = ss;
    __syncthreads();
    for (int st = 128; st > 0; st >>= 1) {
        if (tid < st) { rs[tid] += rs[tid + st]; rss[tid] += rss[tid + st]; }
        __syncthreads();
    }
    if (tid == 0) {
        double invM = 1.0 / (BB * NN);
        double mean = rs[0] * invM;
        double var  = rss[0] * invM - mean * mean;
        float inv = (float)(1.0 / sqrt(var + 1e-5));
        float sc = g[o] * inv;
        s_out[o] = sc;
        t_out[o] = beta[o] - (float)mean * sc;
    }
}

// ---------------- BN+lrelu+max over N, then feat @ wemb^T ----------------
__global__ __launch_bounds__(256) void final_k(const float* __restrict__ y5, const float* __restrict__ s,
                                               const float* __restrict__ t, const float* __restrict__ wemb,
                                               float* __restrict__ out) {
    __shared__ __align__(16) float feat[512];
    int b = blockIdx.x, tid = threadIdx.x;
    for (int o = tid; o < 512; o += 256) {
        float sc = s[o], tt = t[o];
        float m = -INFINITY;
        for (int n = 0; n < NN; n++) {
            float v = sc * y5[(size_t)(b * NN + n) * 512 + o] + tt;
            v = v >= 0.f ? v : 0.2f * v;
            m = fmaxf(m, v);
        }
        feat[o] = m;
    }
    __syncthreads();
    const float4* wr = (const float4*)(wemb + (size_t)tid * 512);
    float acc = 0.f;
    for (int c4 = 0; c4 < 128; c4++) {
        float4 wv = wr[c4];
        float4 fv = *(const float4*)&feat[c4 * 4];
        acc += wv.x * fv.x + wv.y * fv.y + wv.z * fv.z + wv.w * fv.w;
    }
    out[(size_t)b * 256 + tid] = acc;
}

extern "C" void kernel_launch(void* const* d_in, const int* in_sizes, int n_in,
                              void* d_out, int out_size, void* d_ws, size_t ws_size,
                              hipStream_t stream) {
    const float* x    = (const float*)d_in[0];
    const float* w1   = (const float*)d_in[1];
    const float* g1   = (const float*)d_in[2];
    const float* b1   = (const float*)d_in[3];
    const float* w2   = (const float*)d_in[4];
    const float* g2   = (const float*)d_in[5];
    const float* b2   = (const float*)d_in[6];
    const float* w3   = (const float*)d_in[7];
    const float* g3   = (const float*)d_in[8];
    const float* b3   = (const float*)d_in[9];
    const float* w4   = (const float*)d_in[10];
    const float* g4   = (const float*)d_in[11];
    const float* b4   = (const float*)d_in[12];
    const float* w5   = (const float*)d_in[13];
    const float* g5   = (const float*)d_in[14];
    const float* b5   = (const float*)d_in[15];
    const float* wemb = (const float*)d_in[16];
    float* out = (float*)d_out;

    float* fws    = (float*)d_ws;
    float* xtcat  = fws;                                 // 8*1024*512 = 4,194,304
    float* ymax   = xtcat + (size_t)BB * NN * 512;       // 2,097,152
    float* ymin   = ymax + (size_t)BB * NN * 256;        // 2,097,152
    float* y5     = ymax;                                // alias
    float* psum   = ymin + (size_t)BB * NN * 256;        // 2,097,152
    float* psumsq = psum + (size_t)256 * BB * NN;        // 2,097,152
    float* distb  = ymax;                                // alias: 8192*1024 = 8,388,608 = ymax..psumsq
    float* sqn    = psumsq + (size_t)256 * BB * NN;      // 8192
    float* s_arr  = sqn + BB * NN;                       // 512
    float* t_arr  = s_arr + 512;                         // 512
    int*   idxb   = (int*)(t_arr + 512);                 // 8192*20 ints

    const double invM_edge = 1.0 / ((double)BB * NN * KNNK);
    const int nbn = BB * NN;

    // ---- Stage 1: in = x (B,N,3), out ch [0,64) ----
    sqnorm_k<<<(nbn + 255) / 256, 256, 0, stream>>>(x, 3, 0, 3, sqn);
    dist3_k<<<dim3(nbn, 4), 256, 0, stream>>>(x, sqn, distb);
    select_k<<<nbn / 4, 256, 0, stream>>>(distb, idxb);
    edgeconv_k<3, 64><<<nbn, 64, 0, stream>>>(x, 3, 0, idxb, w1, ymax, ymin, psum, psumsq);
    bnstats_k<<<64, 256, 0, stream>>>(psum, psumsq, g1, b1, invM_edge, s_arr, t_arr);
    epilogue_k<64><<<(nbn * 64 + 255) / 256, 256, 0, stream>>>(ymax, ymin, s_arr, t_arr, xtcat, 0);

    // ---- Stage 2: in ch [0,64), out [64,128) ----
    sqnorm_k<<<(nbn + 255) / 256, 256, 0, stream>>>(xtcat, 512, 0, 64, sqn);
    dist_k<64><<<1024, 256, 0, stream>>>(xtcat, 0, sqn, distb);
    select_k<<<nbn / 4, 256, 0, stream>>>(distb, idxb);
    edgeconv_f32<64, 64><<<nbn / 4, 256, 0, stream>>>(xtcat, 0, idxb, w2, ymax, ymin, psum, psumsq);
    bnstats_k<<<64, 256, 0, stream>>>(psum, psumsq, g2, b2, invM_edge, s_arr, t_arr);
    epilogue_k<64><<<(nbn * 64 + 255) / 256, 256, 0, stream>>>(ymax, ymin, s_arr, t_arr, xtcat, 64);

    // ---- Stage 3: in ch [64,128), out [128,256) ----
    sqnorm_k<<<(nbn + 255) / 256, 256, 0, stream>>>(xtcat, 512, 64, 64, sqn);
    dist_k<64><<<1024, 256, 0, stream>>>(xtcat, 64, sqn, distb);
    select_k<<<nbn / 4, 256, 0, stream>>>(distb, idxb);
    edgeconv_f32<64, 128><<<nbn / 4, 256, 0, stream>>>(xtcat, 64, idxb, w3, ymax, ymin, psum, psumsq);
    bnstats_k<<<128, 256, 0, stream>>>(psum, psumsq, g3, b3, invM_edge, s_arr, t_arr);
    epilogue_k<128><<<(nbn * 128 + 255) / 256, 256, 0, stream>>>(ymax, ymin, s_arr, t_arr, xtcat, 128);

    // ---- Stage 4: in ch [128,256), out [256,512), bf16 MFMA ----
    sqnorm_k<<<(nbn + 255) / 256, 256, 0, stream>>>(xtcat, 512, 128, 128, sqn);
    dist_k<128><<<1024, 256, 0, stream>>>(xtcat, 128, sqn, distb);
    select_k<<<nbn / 4, 256, 0, stream>>>(distb, idxb);
    {
        int nblk = (nbn + S4_PTS - 1) / S4_PTS;
        edgeconv4_mfma<<<nblk * 2, 256, 0, stream>>>(xtcat, idxb, w4, ymax, ymin, psum, psumsq);
    }
    bnstats_k<<<256, 256, 0, stream>>>(psum, psumsq, g4, b4, invM_edge, s_arr, t_arr);
    epilogue_k<256><<<(nbn * 256 + 255) / 256, 256, 0, stream>>>(ymax, ymin, s_arr, t_arr, xtcat, 256);

    // ---- Stage 5 ----
    gemm5_k<<<nbn / 16, 256, 0, stream>>>(xtcat, w5, y5);
    bnstats5_k<<<512, 256, 0, stream>>>(y5, g5, b5, s_arr, t_arr);
    final_k<<<BB, 256, 0, stream>>>(y5, s_arr, t_arr, wemb, out);
}

// Round 3
// 1178.401 us; speedup vs baseline: 2.0698x; 1.4164x over previous
//
#include <hip/hip_runtime.h>
#include <math.h>

#define BB 8
#define NN 1024
#define KNNK 20
#define LDC 512

// ---------------- squared norms of rows ----------------
__global__ void sqnorm_k(const float* __restrict__ src, int ld, int off, int C,
                         float* __restrict__ sq) {
    int i = blockIdx.x * blockDim.x + threadIdx.x;
    if (i >= BB * NN) return;
    const float* r = src + (size_t)i * ld + off;
    float s = 0.f;
    for (int c = 0; c < C; c++) { float v = r[c]; s += v * v; }
    sq[i] = s;
}

// ---------------- stage-1 distances (C=3) ----------------
// rank key: 2*dot(q,c) - |c|^2   (dropping -|q|^2: per-query constant, order-preserving)
__global__ void dist3_k(const float* __restrict__ x, const float* __restrict__ sq,
                        float* __restrict__ dist) {
    int q = blockIdx.x;
    int b = q >> 10;
    int cand = blockIdx.y * 256 + threadIdx.x;
    float qx = x[q * 3 + 0], qy = x[q * 3 + 1], qz = x[q * 3 + 2];
    const float* cr = x + (size_t)(b * NN + cand) * 3;
    float d = qx * cr[0] + qy * cr[1] + qz * cr[2];
    dist[(size_t)q * NN + cand] = 2.f * d - sq[b * NN + cand];
}

// ---------------- stages 2-4 distances: GEMM-style, ld=512 ----------------
template<int C>
__global__ __launch_bounds__(256) void dist_k(const float* __restrict__ xt, int off,
                                              const float* __restrict__ sq,
                                              float* __restrict__ dist) {
    int b    = blockIdx.x >> 7;
    int tile = (blockIdx.x >> 3) & 15;
    int qs   = blockIdx.x & 7;
    int lane = threadIdx.x & 63;
    int wv   = __builtin_amdgcn_readfirstlane(threadIdx.x >> 6);
    int cand = tile * 64 + lane;
    float4 row[C / 4];
    const float* rp = xt + (size_t)(b * NN + cand) * LDC + off;
#pragma unroll
    for (int i = 0; i < C / 4; i++) row[i] = *(const float4*)(rp + 4 * i);
    float sqc = sq[b * NN + cand];
    for (int qg = qs * 8 + wv; qg < qs * 8 + 8; qg += 4) {
        int q0 = qg * 16;
        float acc[16];
#pragma unroll
        for (int i = 0; i < 16; i++) acc[i] = 0.f;
        const float* qbase = xt + (size_t)(b * NN + q0) * LDC + off;
#pragma unroll 2
        for (int c4 = 0; c4 < C / 4; c4++) {
            float4 rv = row[c4];
#pragma unroll
            for (int i = 0; i < 16; i++) {
                float4 qv = *(const float4*)(qbase + (size_t)i * LDC + 4 * c4);
                acc[i] += rv.x * qv.x + rv.y * qv.y + rv.z * qv.z + rv.w * qv.w;
            }
        }
#pragma unroll
        for (int i = 0; i < 16; i++)
            dist[(size_t)(b * NN + q0 + i) * NN + cand] = 2.f * acc[i] - sqc;
    }
}

// ---------------- top-20 selection: one wave per query, no barriers ----------------
__global__ __launch_bounds__(256) void select_k(const float* __restrict__ dist,
                                                int* __restrict__ idxout) {
    int q = blockIdx.x * 4 + (threadIdx.x >> 6);
    int lane = threadIdx.x & 63;
    const float* dq = dist + (size_t)q * NN;
    float d[16];
#pragma unroll
    for (int j = 0; j < 16; j++) d[j] = dq[lane + 64 * j];
    for (int t = 0; t < KNNK; t++) {
        float bv = d[0]; int bj = 0;
#pragma unroll
        for (int j = 1; j < 16; j++) if (d[j] > bv) { bv = d[j]; bj = j; }
        int bm = bj * 64 + lane;
        for (int s = 1; s < 64; s <<= 1) {
            float ov = __shfl_xor(bv, s);
            int   om = __shfl_xor(bm, s);
            if (ov > bv || (ov == bv && om < bm)) { bv = ov; bm = om; }
        }
        if (lane == 0) idxout[q * KNNK + t] = bm;
        if ((bm & 63) == lane) {
            int slot = bm >> 6;
#pragma unroll
            for (int j = 0; j < 16; j++) if (j == slot) d[j] = -INFINITY;
        }
    }
}

// ---------------- stage-1 z-gemm (C=3): zf[n][0:64]=Wa.x, [64:128]=Wb.x ----------------
__global__ __launch_bounds__(256) void zgemm3_k(const float* __restrict__ x, const float* __restrict__ w1,
                                                float* __restrict__ zf) {
    int i = blockIdx.x * 256 + threadIdx.x;
    int n = i >> 7, j = i & 127;
    const float* wr = w1 + (j < 64 ? j * 6 : (j - 64) * 6 + 3);
    const float* xr = x + n * 3;
    zf[(size_t)n * 128 + j] = wr[0] * xr[0] + wr[1] * xr[1] + wr[2] * xr[2];
}

// ---------------- z-gemm: zf[n][j] = (j<O ? Wa_j : Wb_{j-O}) . x[n] ----------------
template<int C, int O2>
__global__ __launch_bounds__(256) void zgemm_k(const float* __restrict__ xt, int off,
                                               const float* __restrict__ w,
                                               float* __restrict__ zf) {
    constexpr int O = O2 / 2;
    __shared__ __align__(16) float xs[16][C];
    int p0 = blockIdx.x * 16;
    int tid = threadIdx.x;
    for (int j = tid; j < 16 * (C / 4); j += 256) {
        int p = j / (C / 4), c4 = j % (C / 4);
        *(float4*)&xs[p][4 * c4] = *(const float4*)(xt + (size_t)(p0 + p) * LDC + off + 4 * c4);
    }
    __syncthreads();
    for (int j = tid; j < O2; j += 256) {
        const float* wr = w + (j < O ? (size_t)j * 2 * C : (size_t)(j - O) * 2 * C + C);
        float acc[16];
#pragma unroll
        for (int p = 0; p < 16; p++) acc[p] = 0.f;
        for (int c4 = 0; c4 < C / 4; c4++) {
            float4 wv = *(const float4*)(wr + 4 * c4);
#pragma unroll
            for (int p = 0; p < 16; p++) {
                float4 xv = *(const float4*)&xs[p][4 * c4];
                acc[p] += wv.x * xv.x + wv.y * xv.y + wv.z * xv.z + wv.w * xv.w;
            }
        }
#pragma unroll
        for (int p = 0; p < 16; p++) zf[(size_t)(p0 + p) * O2 + j] = acc[p];
    }
}

// ---------------- gather + stats: wave per point, 20 coalesced row loads ----------------
// y[n,k,o] = z[idx_k,o] + d,  d = zb[n,o]-z[n,o]  (constant over k)
template<int O2>
__global__ __launch_bounds__(256) void gatherstats_k(const float* __restrict__ zf,
                                                     const int* __restrict__ idx,
                                                     float* __restrict__ ymax, float* __restrict__ ymin,
                                                     float* __restrict__ psum, float* __restrict__ psumsq) {
    constexpr int O = O2 / 2;
    int wv = threadIdx.x >> 6, lane = threadIdx.x & 63;
    int n = blockIdx.x * 4 + wv;
    int b = n >> 10;
    const float* zbatch = zf + (size_t)b * NN * O2;
    int nb[KNNK];
#pragma unroll
    for (int k = 0; k < KNNK; k++) nb[k] = idx[n * KNNK + k];
#pragma unroll
    for (int ch = 0; ch < O / 64; ch++) {
        int o = ch * 64 + lane;
        float g[KNNK];
#pragma unroll
        for (int k = 0; k < KNNK; k++) g[k] = zbatch[(size_t)nb[k] * O2 + o];
        float mx = -INFINITY, mn = INFINITY, s = 0.f, ss = 0.f;
#pragma unroll
        for (int k = 0; k < KNNK; k++) {
            float v = g[k];
            mx = fmaxf(mx, v); mn = fminf(mn, v); s += v; ss += v * v;
        }
        float zn  = zf[(size_t)n * O2 + o];
        float zbn = zf[(size_t)n * O2 + O + o];
        float d = zbn - zn;
        mx += d; mn += d;
        ss = ss + 2.f * d * s + (float)KNNK * d * d;
        s  = s + (float)KNNK * d;
        ymax  [(size_t)n * O + o] = mx;
        ymin  [(size_t)n * O + o] = mn;
        psum  [(size_t)n * O + o] = s;
        psumsq[(size_t)n * O + o] = ss;
    }
}

// ---------------- BN reduce pass 1: [8192][O] -> [32][O], fully coalesced ----------------
__global__ __launch_bounds__(256) void bnred1_k(const float* __restrict__ pn, const float* __restrict__ pq,
                                                int O, float* __restrict__ r1s, float* __restrict__ r1q) {
    __shared__ float ls[4][64], lq[4][64];
    int lane = threadIdx.x & 63, wv = threadIdx.x >> 6;
    int o = blockIdx.x * 64 + lane;
    int n0 = blockIdx.y * 256;
    float s = 0.f, q = 0.f;
    for (int r = wv; r < 256; r += 4) {
        s += pn[(size_t)(n0 + r) * O + o];
        q += pq[(size_t)(n0 + r) * O + o];
    }
    ls[wv][lane] = s; lq[wv][lane] = q;
    __syncthreads();
    if (wv == 0) {
        s = ls[0][lane] + ls[1][lane] + ls[2][lane] + ls[3][lane];
        q = lq[0][lane] + lq[1][lane] + lq[2][lane] + lq[3][lane];
        r1s[(size_t)blockIdx.y * O + o] = s;
        r1q[(size_t)blockIdx.y * O + o] = q;
    }
}

// ---------------- pass 1 variant for y5 [8192][512] (sum, sumsq on the fly) ----------------
__global__ __launch_bounds__(256) void bnred1y_k(const float* __restrict__ y5,
                                                 float* __restrict__ r1s, float* __restrict__ r1q) {
    __shared__ float ls[4][64], lq[4][64];
    int lane = threadIdx.x & 63, wv = threadIdx.x >> 6;
    int o = blockIdx.x * 64 + lane;
    int n0 = blockIdx.y * 256;
    float s = 0.f, q = 0.f;
    for (int r = wv; r < 256; r += 4) {
        float v = y5[(size_t)(n0 + r) * 512 + o];
        s += v; q += v * v;
    }
    ls[wv][lane] = s; lq[wv][lane] = q;
    __syncthreads();
    if (wv == 0) {
        s = ls[0][lane] + ls[1][lane] + ls[2][lane] + ls[3][lane];
        q = lq[0][lane] + lq[1][lane] + lq[2][lane] + lq[3][lane];
        r1s[(size_t)blockIdx.y * 512 + o] = s;
        r1q[(size_t)blockIdx.y * 512 + o] = q;
    }
}

// ---------------- BN reduce pass 2 + scale/shift ----------------
__global__ __launch_bounds__(64) void bnred2_k(const float* __restrict__ r1s, const float* __restrict__ r1q,
                                               const float* __restrict__ g, const float* __restrict__ beta,
                                               int O, double invM,
                                               float* __restrict__ s_out, float* __restrict__ t_out) {
    int o = blockIdx.x, lane = threadIdx.x;
    double s = 0.0, q = 0.0;
    if (lane < 32) { s = r1s[(size_t)lane * O + o]; q = r1q[(size_t)lane * O + o]; }
#pragma unroll
    for (int m = 1; m < 32; m <<= 1) { s += __shfl_xor(s, m); q += __shfl_xor(q, m); }
    if (lane == 0) {
        double mean = s * invM;
        double var = q * invM - mean * mean;
        float inv = (float)(1.0 / sqrt(var + 1e-5));
        float sc = g[o] * inv;
        s_out[o] = sc;
        t_out[o] = beta[o] - (float)mean * sc;
    }
}

// ---------------- BN+lrelu on max/min (monotone), write into cat buffer ----------------
template<int O>
__global__ void epilogue_k(const float* __restrict__ ymax, const float* __restrict__ ymin,
                           const float* __restrict__ s, const float* __restrict__ t,
                           float* __restrict__ xtcat, int off_out) {
    int i = blockIdx.x * blockDim.x + threadIdx.x;
    if (i >= BB * NN * O) return;
    int bn = i / O;
    int o = i & (O - 1);
    float sc = s[o];
    float v = sc >= 0.f ? ymax[i] : ymin[i];
    float y = sc * v + t[o];
    y = y >= 0.f ? y : 0.2f * y;
    xtcat[(size_t)bn * LDC + off_out + o] = y;
}

// ---------------- stage 5: y5 = w5 @ cat ----------------
__global__ __launch_bounds__(256) void gemm5_k(const float* __restrict__ xtcat, const float* __restrict__ w5,
                                               float* __restrict__ y5) {
    __shared__ __align__(16) float rows[16][512];
    int bn0 = blockIdx.x * 16;
    int tid = threadIdx.x;
    for (int j = tid; j < 16 * 512; j += 256) ((float*)rows)[j] = xtcat[(size_t)bn0 * 512 + j];
    __syncthreads();
    for (int o = tid; o < 512; o += 256) {
        const float4* wr = (const float4*)(w5 + (size_t)o * 512);
        float acc[16];
#pragma unroll
        for (int i = 0; i < 16; i++) acc[i] = 0.f;
        for (int c4 = 0; c4 < 128; c4++) {
            float4 wv = wr[c4];
#pragma unroll
            for (int i = 0; i < 16; i++) {
                float4 rv = *(const float4*)&rows[i][c4 * 4];
                acc[i] += wv.x * rv.x + wv.y * rv.y + wv.z * rv.z + wv.w * rv.w;
            }
        }
#pragma unroll
        for (int i = 0; i < 16; i++) y5[(size_t)(bn0 + i) * 512 + o] = acc[i];
    }
}

// ---------------- BN+lrelu+max over N, then feat @ wemb^T ----------------
__global__ __launch_bounds__(256) void final_k(const float* __restrict__ y5, const float* __restrict__ s,
                                               const float* __restrict__ t, const float* __restrict__ wemb,
                                               float* __restrict__ out) {
    __shared__ __align__(16) float feat[512];
    int b = blockIdx.x, tid = threadIdx.x;
    for (int o = tid; o < 512; o += 256) {
        float sc = s[o], tt = t[o];
        float m = -INFINITY;
        for (int n = 0; n < NN; n++) {
            float v = sc * y5[(size_t)(b * NN + n) * 512 + o] + tt;
            v = v >= 0.f ? v : 0.2f * v;
            m = fmaxf(m, v);
        }
        feat[o] = m;
    }
    __syncthreads();
    const float4* wr = (const float4*)(wemb + (size_t)tid * 512);
    float acc = 0.f;
    for (int c4 = 0; c4 < 128; c4++) {
        float4 wv = wr[c4];
        float4 fv = *(const float4*)&feat[c4 * 4];
        acc += wv.x * fv.x + wv.y * fv.y + wv.z * fv.z + wv.w * fv.w;
    }
    out[(size_t)b * 256 + tid] = acc;
}

extern "C" void kernel_launch(void* const* d_in, const int* in_sizes, int n_in,
                              void* d_out, int out_size, void* d_ws, size_t ws_size,
                              hipStream_t stream) {
    const float* x    = (const float*)d_in[0];
    const float* w1   = (const float*)d_in[1];
    const float* g1   = (const float*)d_in[2];
    const float* b1   = (const float*)d_in[3];
    const float* w2   = (const float*)d_in[4];
    const float* g2   = (const float*)d_in[5];
    const float* b2   = (const float*)d_in[6];
    const float* w3   = (const float*)d_in[7];
    const float* g3   = (const float*)d_in[8];
    const float* b3   = (const float*)d_in[9];
    const float* w4   = (const float*)d_in[10];
    const float* g4   = (const float*)d_in[11];
    const float* b4   = (const float*)d_in[12];
    const float* w5   = (const float*)d_in[13];
    const float* g5   = (const float*)d_in[14];
    const float* b5   = (const float*)d_in[15];
    const float* wemb = (const float*)d_in[16];
    float* out = (float*)d_out;

    float* fws    = (float*)d_ws;
    float* xtcat  = fws;                                 // 4,194,304
    float* ymax   = xtcat + (size_t)BB * NN * 512;       // 2,097,152
    float* ymin   = ymax + (size_t)BB * NN * 256;        // 2,097,152
    float* psum   = ymin + (size_t)BB * NN * 256;        // 2,097,152
    float* psumsq = psum + (size_t)BB * NN * 256;        // 2,097,152
    float* distb  = ymax;                                // alias: 8192*1024 = ymax..psumsq (dead before gatherstats)
    float* y5     = ymax;                                // alias: 8192*512 = ymax+ymin (stage 5)
    float* sqn    = psumsq + (size_t)BB * NN * 256;      // 8192
    float* s_arr  = sqn + BB * NN;                       // 512
    float* t_arr  = s_arr + 512;                         // 512
    float* r1s    = t_arr + 512;                         // 32*512 = 16384
    float* r1q    = r1s + 32 * 512;                      // 16384
    int*   idxb   = (int*)(r1q + 32 * 512);              // 8192*20 ints
    float* zfull  = (float*)(idxb + BB * NN * KNNK);     // 8192*512 = 4,194,304

    const double invM_edge = 1.0 / ((double)BB * NN * KNNK);
    const int nbn = BB * NN;

    // ---- Stage 1: in = x (B,N,3), out ch [0,64) ----
    sqnorm_k<<<(nbn + 255) / 256, 256, 0, stream>>>(x, 3, 0, 3, sqn);
    dist3_k<<<dim3(nbn, 4), 256, 0, stream>>>(x, sqn, distb);
    select_k<<<nbn / 4, 256, 0, stream>>>(distb, idxb);
    zgemm3_k<<<nbn * 128 / 256, 256, 0, stream>>>(x, w1, zfull);
    gatherstats_k<128><<<nbn / 4, 256, 0, stream>>>(zfull, idxb, ymax, ymin, psum, psumsq);
    bnred1_k<<<dim3(1, 32), 256, 0, stream>>>(psum, psumsq, 64, r1s, r1q);
    bnred2_k<<<64, 64, 0, stream>>>(r1s, r1q, g1, b1, 64, invM_edge, s_arr, t_arr);
    epilogue_k<64><<<(nbn * 64 + 255) / 256, 256, 0, stream>>>(ymax, ymin, s_arr, t_arr, xtcat, 0);

    // ---- Stage 2: in ch [0,64), out [64,128) ----
    sqnorm_k<<<(nbn + 255) / 256, 256, 0, stream>>>(xtcat, 512, 0, 64, sqn);
    dist_k<64><<<1024, 256, 0, stream>>>(xtcat, 0, sqn, distb);
    select_k<<<nbn / 4, 256, 0, stream>>>(distb, idxb);
    zgemm_k<64, 128><<<nbn / 16, 256, 0, stream>>>(xtcat, 0, w2, zfull);
    gatherstats_k<128><<<nbn / 4, 256, 0, stream>>>(zfull, idxb, ymax, ymin, psum, psumsq);
    bnred1_k<<<dim3(1, 32), 256, 0, stream>>>(psum, psumsq, 64, r1s, r1q);
    bnred2_k<<<64, 64, 0, stream>>>(r1s, r1q, g2, b2, 64, invM_edge, s_arr, t_arr);
    epilogue_k<64><<<(nbn * 64 + 255) / 256, 256, 0, stream>>>(ymax, ymin, s_arr, t_arr, xtcat, 64);

    // ---- Stage 3: in ch [64,128), out [128,256) ----
    sqnorm_k<<<(nbn + 255) / 256, 256, 0, stream>>>(xtcat, 512, 64, 64, sqn);
    dist_k<64><<<1024, 256, 0, stream>>>(xtcat, 64, sqn, distb);
    select_k<<<nbn / 4, 256, 0, stream>>>(distb, idxb);
    zgemm_k<64, 256><<<nbn / 16, 256, 0, stream>>>(xtcat, 64, w3, zfull);
    gatherstats_k<256><<<nbn / 4, 256, 0, stream>>>(zfull, idxb, ymax, ymin, psum, psumsq);
    bnred1_k<<<dim3(2, 32), 256, 0, stream>>>(psum, psumsq, 128, r1s, r1q);
    bnred2_k<<<128, 64, 0, stream>>>(r1s, r1q, g3, b3, 128, invM_edge, s_arr, t_arr);
    epilogue_k<128><<<(nbn * 128 + 255) / 256, 256, 0, stream>>>(ymax, ymin, s_arr, t_arr, xtcat, 128);

    // ---- Stage 4: in ch [128,256), out [256,512) ----
    sqnorm_k<<<(nbn + 255) / 256, 256, 0, stream>>>(xtcat, 512, 128, 128, sqn);
    dist_k<128><<<1024, 256, 0, stream>>>(xtcat, 128, sqn, distb);
    select_k<<<nbn / 4, 256, 0, stream>>>(distb, idxb);
    zgemm_k<128, 512><<<nbn / 16, 256, 0, stream>>>(xtcat, 128, w4, zfull);
    gatherstats_k<512><<<nbn / 4, 256, 0, stream>>>(zfull, idxb, ymax, ymin, psum, psumsq);
    bnred1_k<<<dim3(4, 32), 256, 0, stream>>>(psum, psumsq, 256, r1s, r1q);
    bnred2_k<<<256, 64, 0, stream>>>(r1s, r1q, g4, b4, 256, invM_edge, s_arr, t_arr);
    epilogue_k<256><<<(nbn * 256 + 255) / 256, 256, 0, stream>>>(ymax, ymin, s_arr, t_arr, xtcat, 256);

    // ---- Stage 5 ----
    gemm5_k<<<nbn / 16, 256, 0, stream>>>(xtcat, w5, y5);
    bnred1y_k<<<dim3(8, 32), 256, 0, stream>>>(y5, r1s, r1q);
    bnred2_k<<<512, 64, 0, stream>>>(r1s, r1q, g5, b5, 512, 1.0 / (BB * NN), s_arr, t_arr);
    final_k<<<BB, 256, 0, stream>>>(y5, s_arr, t_arr, wemb, out);
}

// Round 4
// 907.285 us; speedup vs baseline: 2.6883x; 1.2988x over previous
//
#include <hip/hip_runtime.h>
#include <math.h>

#define BB 8
#define NN 1024
#define KNNK 20
#define LDC 512

// ---------------- squared norms of rows ----------------
__global__ void sqnorm_k(const float* __restrict__ src, int ld, int off, int C,
                         float* __restrict__ sq) {
    int i = blockIdx.x * blockDim.x + threadIdx.x;
    if (i >= BB * NN) return;
    const float* r = src + (size_t)i * ld + off;
    float s = 0.f;
    for (int c = 0; c < C; c++) { float v = r[c]; s += v * v; }
    sq[i] = s;
}

// ---------------- stage-1 distances (C=3) ----------------
// rank key: 2*dot(q,c) - |c|^2   (dropping -|q|^2: per-query constant, order-preserving)
__global__ void dist3_k(const float* __restrict__ x, const float* __restrict__ sq,
                        float* __restrict__ dist) {
    int q = blockIdx.x;
    int b = q >> 10;
    int cand = blockIdx.y * 256 + threadIdx.x;
    float qx = x[q * 3 + 0], qy = x[q * 3 + 1], qz = x[q * 3 + 2];
    const float* cr = x + (size_t)(b * NN + cand) * 3;
    float d = qx * cr[0] + qy * cr[1] + qz * cr[2];
    dist[(size_t)q * NN + cand] = 2.f * d - sq[b * NN + cand];
}

// ---------------- stages 2-4 distances: GEMM-style, ld=512 ----------------
template<int C>
__global__ __launch_bounds__(256) void dist_k(const float* __restrict__ xt, int off,
                                              const float* __restrict__ sq,
                                              float* __restrict__ dist) {
    int b    = blockIdx.x >> 7;
    int tile = (blockIdx.x >> 3) & 15;
    int qs   = blockIdx.x & 7;
    int lane = threadIdx.x & 63;
    int wv   = __builtin_amdgcn_readfirstlane(threadIdx.x >> 6);
    int cand = tile * 64 + lane;
    float4 row[C / 4];
    const float* rp = xt + (size_t)(b * NN + cand) * LDC + off;
#pragma unroll
    for (int i = 0; i < C / 4; i++) row[i] = *(const float4*)(rp + 4 * i);
    float sqc = sq[b * NN + cand];
    for (int qg = qs * 8 + wv; qg < qs * 8 + 8; qg += 4) {
        int q0 = qg * 16;
        float acc[16];
#pragma unroll
        for (int i = 0; i < 16; i++) acc[i] = 0.f;
        const float* qbase = xt + (size_t)(b * NN + q0) * LDC + off;
#pragma unroll 2
        for (int c4 = 0; c4 < C / 4; c4++) {
            float4 rv = row[c4];
#pragma unroll
            for (int i = 0; i < 16; i++) {
                float4 qv = *(const float4*)(qbase + (size_t)i * LDC + 4 * c4);
                acc[i] += rv.x * qv.x + rv.y * qv.y + rv.z * qv.z + rv.w * qv.w;
            }
        }
#pragma unroll
        for (int i = 0; i < 16; i++)
            dist[(size_t)(b * NN + q0 + i) * NN + cand] = 2.f * acc[i] - sqc;
    }
}

// ---------------- top-20 selection: one wave per query, no barriers ----------------
__global__ __launch_bounds__(256) void select_k(const float* __restrict__ dist,
                                                int* __restrict__ idxout) {
    int q = blockIdx.x * 4 + (threadIdx.x >> 6);
    int lane = threadIdx.x & 63;
    const float* dq = dist + (size_t)q * NN;
    float d[16];
#pragma unroll
    for (int j = 0; j < 16; j++) d[j] = dq[lane + 64 * j];
    for (int t = 0; t < KNNK; t++) {
        float bv = d[0]; int bj = 0;
#pragma unroll
        for (int j = 1; j < 16; j++) if (d[j] > bv) { bv = d[j]; bj = j; }
        int bm = bj * 64 + lane;
        for (int s = 1; s < 64; s <<= 1) {
            float ov = __shfl_xor(bv, s);
            int   om = __shfl_xor(bm, s);
            if (ov > bv || (ov == bv && om < bm)) { bv = ov; bm = om; }
        }
        if (lane == 0) idxout[q * KNNK + t] = bm;
        if ((bm & 63) == lane) {
            int slot = bm >> 6;
#pragma unroll
            for (int j = 0; j < 16; j++) if (j == slot) d[j] = -INFINITY;
        }
    }
}

// ---------------- stage-1 z-gemm (C=3): zf[n][0:64]=Wa.x, [64:128]=Wb.x ----------------
__global__ __launch_bounds__(256) void zgemm3_k(const float* __restrict__ x, const float* __restrict__ w1,
                                                float* __restrict__ zf) {
    int i = blockIdx.x * 256 + threadIdx.x;
    int n = i >> 7, j = i & 127;
    const float* wr = w1 + (j < 64 ? j * 6 : (j - 64) * 6 + 3);
    const float* xr = x + n * 3;
    zf[(size_t)n * 128 + j] = wr[0] * xr[0] + wr[1] * xr[1] + wr[2] * xr[2];
}

// ---------------- z-gemm: zf[n][j] = (j<O ? Wa_j : Wb_{j-O}) . x[n] ----------------
template<int C, int O2>
__global__ __launch_bounds__(256) void zgemm_k(const float* __restrict__ xt, int off,
                                               const float* __restrict__ w,
                                               float* __restrict__ zf) {
    constexpr int O = O2 / 2;
    __shared__ __align__(16) float xs[16][C];
    int p0 = blockIdx.x * 16;
    int tid = threadIdx.x;
    for (int j = tid; j < 16 * (C / 4); j += 256) {
        int p = j / (C / 4), c4 = j % (C / 4);
        *(float4*)&xs[p][4 * c4] = *(const float4*)(xt + (size_t)(p0 + p) * LDC + off + 4 * c4);
    }
    __syncthreads();
    for (int j = tid; j < O2; j += 256) {
        const float* wr = w + (j < O ? (size_t)j * 2 * C : (size_t)(j - O) * 2 * C + C);
        float acc[16];
#pragma unroll
        for (int p = 0; p < 16; p++) acc[p] = 0.f;
        for (int c4 = 0; c4 < C / 4; c4++) {
            float4 wv = *(const float4*)(wr + 4 * c4);
#pragma unroll
            for (int p = 0; p < 16; p++) {
                float4 xv = *(const float4*)&xs[p][4 * c4];
                acc[p] += wv.x * xv.x + wv.y * xv.y + wv.z * xv.z + wv.w * xv.w;
            }
        }
#pragma unroll
        for (int p = 0; p < 16; p++) zf[(size_t)(p0 + p) * O2 + j] = acc[p];
    }
}

// ---------------- gather + stats: wave per point, 20 coalesced row loads ----------------
// y[n,k,o] = z[idx_k,o] + d,  d = zb[n,o]-z[n,o]  (constant over k)
template<int O2>
__global__ __launch_bounds__(256) void gatherstats_k(const float* __restrict__ zf,
                                                     const int* __restrict__ idx,
                                                     float* __restrict__ ymax, float* __restrict__ ymin,
                                                     float* __restrict__ psum, float* __restrict__ psumsq) {
    constexpr int O = O2 / 2;
    int wv = threadIdx.x >> 6, lane = threadIdx.x & 63;
    int n = blockIdx.x * 4 + wv;
    int b = n >> 10;
    const float* zbatch = zf + (size_t)b * NN * O2;
    int nb[KNNK];
#pragma unroll
    for (int k = 0; k < KNNK; k++) nb[k] = idx[n * KNNK + k];
#pragma unroll
    for (int ch = 0; ch < O / 64; ch++) {
        int o = ch * 64 + lane;
        float g[KNNK];
#pragma unroll
        for (int k = 0; k < KNNK; k++) g[k] = zbatch[(size_t)nb[k] * O2 + o];
        float mx = -INFINITY, mn = INFINITY, s = 0.f, ss = 0.f;
#pragma unroll
        for (int k = 0; k < KNNK; k++) {
            float v = g[k];
            mx = fmaxf(mx, v); mn = fminf(mn, v); s += v; ss += v * v;
        }
        float zn  = zf[(size_t)n * O2 + o];
        float zbn = zf[(size_t)n * O2 + O + o];
        float d = zbn - zn;
        mx += d; mn += d;
        ss = ss + 2.f * d * s + (float)KNNK * d * d;
        s  = s + (float)KNNK * d;
        ymax  [(size_t)n * O + o] = mx;
        ymin  [(size_t)n * O + o] = mn;
        psum  [(size_t)n * O + o] = s;
        psumsq[(size_t)n * O + o] = ss;
    }
}

// ---------------- BN reduce pass 1: [8192][O] -> [32][O], fully coalesced ----------------
__global__ __launch_bounds__(256) void bnred1_k(const float* __restrict__ pn, const float* __restrict__ pq,
                                                int O, float* __restrict__ r1s, float* __restrict__ r1q) {
    __shared__ float ls[4][64], lq[4][64];
    int lane = threadIdx.x & 63, wv = threadIdx.x >> 6;
    int o = blockIdx.x * 64 + lane;
    int n0 = blockIdx.y * 256;
    float s = 0.f, q = 0.f;
    for (int r = wv; r < 256; r += 4) {
        s += pn[(size_t)(n0 + r) * O + o];
        q += pq[(size_t)(n0 + r) * O + o];
    }
    ls[wv][lane] = s; lq[wv][lane] = q;
    __syncthreads();
    if (wv == 0) {
        s = ls[0][lane] + ls[1][lane] + ls[2][lane] + ls[3][lane];
        q = lq[0][lane] + lq[1][lane] + lq[2][lane] + lq[3][lane];
        r1s[(size_t)blockIdx.y * O + o] = s;
        r1q[(size_t)blockIdx.y * O + o] = q;
    }
}

// ---------------- BN reduce pass 2 + scale/shift ----------------
__global__ __launch_bounds__(64) void bnred2_k(const float* __restrict__ r1s, const float* __restrict__ r1q,
                                               const float* __restrict__ g, const float* __restrict__ beta,
                                               int O, double invM,
                                               float* __restrict__ s_out, float* __restrict__ t_out) {
    int o = blockIdx.x, lane = threadIdx.x;
    double s = 0.0, q = 0.0;
    if (lane < 32) { s = r1s[(size_t)lane * O + o]; q = r1q[(size_t)lane * O + o]; }
#pragma unroll
    for (int m = 1; m < 32; m <<= 1) { s += __shfl_xor(s, m); q += __shfl_xor(q, m); }
    if (lane == 0) {
        double mean = s * invM;
        double var = q * invM - mean * mean;
        float inv = (float)(1.0 / sqrt(var + 1e-5));
        float sc = g[o] * inv;
        s_out[o] = sc;
        t_out[o] = beta[o] - (float)mean * sc;
    }
}

// ---------------- BN+lrelu on max/min (monotone), write into cat buffer ----------------
template<int O>
__global__ void epilogue_k(const float* __restrict__ ymax, const float* __restrict__ ymin,
                           const float* __restrict__ s, const float* __restrict__ t,
                           float* __restrict__ xtcat, int off_out) {
    int i = blockIdx.x * blockDim.x + threadIdx.x;
    if (i >= BB * NN * O) return;
    int bn = i / O;
    int o = i & (O - 1);
    float sc = s[o];
    float v = sc >= 0.f ? ymax[i] : ymin[i];
    float y = sc * v + t[o];
    y = y >= 0.f ? y : 0.2f * y;
    xtcat[(size_t)bn * LDC + off_out + o] = y;
}

// ---------------- stage 5: w5 @ cat with fused per-16-row stats (y5 never hits HBM) ----------------
__global__ __launch_bounds__(256) void gemm5_k(const float* __restrict__ xtcat, const float* __restrict__ w5,
                                               float* __restrict__ pmax, float* __restrict__ pmn,
                                               float* __restrict__ ps, float* __restrict__ pq) {
    __shared__ __align__(16) float rows[16][512];
    int bn0 = blockIdx.x * 16;
    int tid = threadIdx.x;
    for (int j = tid; j < 16 * 512; j += 256) ((float*)rows)[j] = xtcat[(size_t)bn0 * 512 + j];
    __syncthreads();
    for (int o = tid; o < 512; o += 256) {
        const float4* wr = (const float4*)(w5 + (size_t)o * 512);
        float acc[16];
#pragma unroll
        for (int i = 0; i < 16; i++) acc[i] = 0.f;
        for (int c4 = 0; c4 < 128; c4++) {
            float4 wv = wr[c4];
#pragma unroll
            for (int i = 0; i < 16; i++) {
                float4 rv = *(const float4*)&rows[i][c4 * 4];
                acc[i] += wv.x * rv.x + wv.y * rv.y + wv.z * rv.z + wv.w * rv.w;
            }
        }
        float mx = -INFINITY, mn = INFINITY, s = 0.f, ss = 0.f;
#pragma unroll
        for (int i = 0; i < 16; i++) {
            float v = acc[i];
            mx = fmaxf(mx, v); mn = fminf(mn, v); s += v; ss += v * v;
        }
        pmax[(size_t)blockIdx.x * 512 + o] = mx;
        pmn [(size_t)blockIdx.x * 512 + o] = mn;
        ps  [(size_t)blockIdx.x * 512 + o] = s;
        pq  [(size_t)blockIdx.x * 512 + o] = ss;
    }
}

// ---------------- stage-5 BN stats from the 512 per-block partials ----------------
__global__ __launch_bounds__(256) void bnstat5_k(const float* __restrict__ ps, const float* __restrict__ pq,
                                                 const float* __restrict__ g, const float* __restrict__ beta,
                                                 float* __restrict__ s_out, float* __restrict__ t_out) {
    __shared__ double lds_s[4][64], lds_q[4][64];
    int lane = threadIdx.x & 63, wv = threadIdx.x >> 6;
    int o = blockIdx.x * 64 + lane;
    double s = 0.0, q = 0.0;
    for (int r = wv; r < 512; r += 4) {
        s += ps[(size_t)r * 512 + o];
        q += pq[(size_t)r * 512 + o];
    }
    lds_s[wv][lane] = s; lds_q[wv][lane] = q;
    __syncthreads();
    if (wv == 0) {
        s = lds_s[0][lane] + lds_s[1][lane] + lds_s[2][lane] + lds_s[3][lane];
        q = lds_q[0][lane] + lds_q[1][lane] + lds_q[2][lane] + lds_q[3][lane];
        double invM = 1.0 / (BB * NN);
        double mean = s * invM;
        double var = q * invM - mean * mean;
        float inv = (float)(1.0 / sqrt(var + 1e-5));
        float sc = g[o] * inv;
        s_out[o] = sc;
        t_out[o] = beta[o] - (float)mean * sc;
    }
}

// ---------------- per-batch max/min reduce + BN + lrelu + feat @ wemb^T ----------------
__global__ __launch_bounds__(256) void featgemm_k(const float* __restrict__ pmax, const float* __restrict__ pmn,
                                                  const float* __restrict__ s, const float* __restrict__ t,
                                                  const float* __restrict__ wemb, float* __restrict__ out) {
    __shared__ __align__(16) float feat[512];
    int b = blockIdx.x, tid = threadIdx.x;
    for (int o = tid; o < 512; o += 256) {
        float mx = -INFINITY, mn = INFINITY;
        for (int r = b * 64; r < (b + 1) * 64; r++) {
            mx = fmaxf(mx, pmax[(size_t)r * 512 + o]);
            mn = fminf(mn, pmn [(size_t)r * 512 + o]);
        }
        float sc = s[o];
        float v = sc >= 0.f ? mx : mn;
        float y = sc * v + t[o];
        feat[o] = y >= 0.f ? y : 0.2f * y;
    }
    __syncthreads();
    const float4* wr = (const float4*)(wemb + (size_t)tid * 512);
    float acc = 0.f;
    for (int c4 = 0; c4 < 128; c4++) {
        float4 wv = wr[c4];
        float4 fv = *(const float4*)&feat[c4 * 4];
        acc += wv.x * fv.x + wv.y * fv.y + wv.z * fv.z + wv.w * fv.w;
    }
    out[(size_t)b * 256 + tid] = acc;
}

extern "C" void kernel_launch(void* const* d_in, const int* in_sizes, int n_in,
                              void* d_out, int out_size, void* d_ws, size_t ws_size,
                              hipStream_t stream) {
    const float* x    = (const float*)d_in[0];
    const float* w1   = (const float*)d_in[1];
    const float* g1   = (const float*)d_in[2];
    const float* b1   = (const float*)d_in[3];
    const float* w2   = (const float*)d_in[4];
    const float* g2   = (const float*)d_in[5];
    const float* b2   = (const float*)d_in[6];
    const float* w3   = (const float*)d_in[7];
    const float* g3   = (const float*)d_in[8];
    const float* b3   = (const float*)d_in[9];
    const float* w4   = (const float*)d_in[10];
    const float* g4   = (const float*)d_in[11];
    const float* b4   = (const float*)d_in[12];
    const float* w5   = (const float*)d_in[13];
    const float* g5   = (const float*)d_in[14];
    const float* b5   = (const float*)d_in[15];
    const float* wemb = (const float*)d_in[16];
    float* out = (float*)d_out;

    float* fws    = (float*)d_ws;
    float* xtcat  = fws;                                 // 4,194,304
    float* ymax   = xtcat + (size_t)BB * NN * 512;       // 2,097,152
    float* ymin   = ymax + (size_t)BB * NN * 256;        // 2,097,152
    float* psum   = ymin + (size_t)BB * NN * 256;        // 2,097,152
    float* psumsq = psum + (size_t)BB * NN * 256;        // 2,097,152
    float* distb  = ymax;                                // alias: 8192*1024 floats (dead before gatherstats)
    float* pmax   = ymax;                                // alias: stage-5 partials, 512*512 each
    float* pmn    = pmax + 512 * 512;
    float* ps5    = pmn + 512 * 512;
    float* pq5    = ps5 + 512 * 512;
    float* sqn    = psumsq + (size_t)BB * NN * 256;      // 8192
    float* s_arr  = sqn + BB * NN;                       // 512
    float* t_arr  = s_arr + 512;                         // 512
    float* r1s    = t_arr + 512;                         // 32*512
    float* r1q    = r1s + 32 * 512;                      // 32*512
    int*   idxb   = (int*)(r1q + 32 * 512);              // 8192*20 ints
    float* zfull  = (float*)(idxb + BB * NN * KNNK);     // 8192*512

    const double invM_edge = 1.0 / ((double)BB * NN * KNNK);
    const int nbn = BB * NN;

    // ---- Stage 1: in = x (B,N,3), out ch [0,64) ----
    sqnorm_k<<<(nbn + 255) / 256, 256, 0, stream>>>(x, 3, 0, 3, sqn);
    dist3_k<<<dim3(nbn, 4), 256, 0, stream>>>(x, sqn, distb);
    select_k<<<nbn / 4, 256, 0, stream>>>(distb, idxb);
    zgemm3_k<<<nbn * 128 / 256, 256, 0, stream>>>(x, w1, zfull);
    gatherstats_k<128><<<nbn / 4, 256, 0, stream>>>(zfull, idxb, ymax, ymin, psum, psumsq);
    bnred1_k<<<dim3(1, 32), 256, 0, stream>>>(psum, psumsq, 64, r1s, r1q);
    bnred2_k<<<64, 64, 0, stream>>>(r1s, r1q, g1, b1, 64, invM_edge, s_arr, t_arr);
    epilogue_k<64><<<(nbn * 64 + 255) / 256, 256, 0, stream>>>(ymax, ymin, s_arr, t_arr, xtcat, 0);

    // ---- Stage 2: in ch [0,64), out [64,128) ----
    sqnorm_k<<<(nbn + 255) / 256, 256, 0, stream>>>(xtcat, 512, 0, 64, sqn);
    dist_k<64><<<1024, 256, 0, stream>>>(xtcat, 0, sqn, distb);
    select_k<<<nbn / 4, 256, 0, stream>>>(distb, idxb);
    zgemm_k<64, 128><<<nbn / 16, 256, 0, stream>>>(xtcat, 0, w2, zfull);
    gatherstats_k<128><<<nbn / 4, 256, 0, stream>>>(zfull, idxb, ymax, ymin, psum, psumsq);
    bnred1_k<<<dim3(1, 32), 256, 0, stream>>>(psum, psumsq, 64, r1s, r1q);
    bnred2_k<<<64, 64, 0, stream>>>(r1s, r1q, g2, b2, 64, invM_edge, s_arr, t_arr);
    epilogue_k<64><<<(nbn * 64 + 255) / 256, 256, 0, stream>>>(ymax, ymin, s_arr, t_arr, xtcat, 64);

    // ---- Stage 3: in ch [64,128), out [128,256) ----
    sqnorm_k<<<(nbn + 255) / 256, 256, 0, stream>>>(xtcat, 512, 64, 64, sqn);
    dist_k<64><<<1024, 256, 0, stream>>>(xtcat, 64, sqn, distb);
    select_k<<<nbn / 4, 256, 0, stream>>>(distb, idxb);
    zgemm_k<64, 256><<<nbn / 16, 256, 0, stream>>>(xtcat, 64, w3, zfull);
    gatherstats_k<256><<<nbn / 4, 256, 0, stream>>>(zfull, idxb, ymax, ymin, psum, psumsq);
    bnred1_k<<<dim3(2, 32), 256, 0, stream>>>(psum, psumsq, 128, r1s, r1q);
    bnred2_k<<<128, 64, 0, stream>>>(r1s, r1q, g3, b3, 128, invM_edge, s_arr, t_arr);
    epilogue_k<128><<<(nbn * 128 + 255) / 256, 256, 0, stream>>>(ymax, ymin, s_arr, t_arr, xtcat, 128);

    // ---- Stage 4: in ch [128,256), out [256,512) ----
    sqnorm_k<<<(nbn + 255) / 256, 256, 0, stream>>>(xtcat, 512, 128, 128, sqn);
    dist_k<128><<<1024, 256, 0, stream>>>(xtcat, 128, sqn, distb);
    select_k<<<nbn / 4, 256, 0, stream>>>(distb, idxb);
    zgemm_k<128, 512><<<nbn / 16, 256, 0, stream>>>(xtcat, 128, w4, zfull);
    gatherstats_k<512><<<nbn / 4, 256, 0, stream>>>(zfull, idxb, ymax, ymin, psum, psumsq);
    bnred1_k<<<dim3(4, 32), 256, 0, stream>>>(psum, psumsq, 256, r1s, r1q);
    bnred2_k<<<256, 64, 0, stream>>>(r1s, r1q, g4, b4, 256, invM_edge, s_arr, t_arr);
    epilogue_k<256><<<(nbn * 256 + 255) / 256, 256, 0, stream>>>(ymax, ymin, s_arr, t_arr, xtcat, 256);

    // ---- Stage 5: fused GEMM+stats, then tiny reductions ----
    gemm5_k<<<nbn / 16, 256, 0, stream>>>(xtcat, w5, pmax, pmn, ps5, pq5);
    bnstat5_k<<<8, 256, 0, stream>>>(ps5, pq5, g5, b5, s_arr, t_arr);
    featgemm_k<<<BB, 256, 0, stream>>>(pmax, pmn, s_arr, t_arr, wemb, out);
}

// Round 5
// 788.386 us; speedup vs baseline: 3.0937x; 1.1508x over previous
//
#include <hip/hip_runtime.h>
#include <hip/hip_bf16.h>
#include <math.h>

#define BB 8
#define NN 1024
#define KNNK 20
#define LDC 512

typedef __attribute__((ext_vector_type(8))) short bfrag8;
typedef __attribute__((ext_vector_type(4))) float facc4;

struct bh8 { __hip_bfloat16 h[8]; };

// ---------------- fp32 -> bf16 convert (8 elems/thread) ----------------
__global__ __launch_bounds__(256) void f2bf_k(const float* __restrict__ in,
                                              __hip_bfloat16* __restrict__ out, int n) {
    int i = (blockIdx.x * 256 + threadIdx.x) * 8;
    if (i >= n) return;
    float4 a = *(const float4*)(in + i);
    float4 b = *(const float4*)(in + i + 4);
    bh8 v;
    v.h[0] = __float2bfloat16(a.x); v.h[1] = __float2bfloat16(a.y);
    v.h[2] = __float2bfloat16(a.z); v.h[3] = __float2bfloat16(a.w);
    v.h[4] = __float2bfloat16(b.x); v.h[5] = __float2bfloat16(b.y);
    v.h[6] = __float2bfloat16(b.z); v.h[7] = __float2bfloat16(b.w);
    *(bh8*)(out + i) = v;
}

// ---------------- squared norms of rows ----------------
__global__ void sqnorm_k(const float* __restrict__ src, int ld, int off, int C,
                         float* __restrict__ sq) {
    int i = blockIdx.x * blockDim.x + threadIdx.x;
    if (i >= BB * NN) return;
    const float* r = src + (size_t)i * ld + off;
    float s = 0.f;
    for (int c = 0; c < C; c++) { float v = r[c]; s += v * v; }
    sq[i] = s;
}

// ---------------- stage-1 distances (C=3) ----------------
__global__ void dist3_k(const float* __restrict__ x, const float* __restrict__ sq,
                        float* __restrict__ dist) {
    int q = blockIdx.x;
    int b = q >> 10;
    int cand = blockIdx.y * 256 + threadIdx.x;
    float qx = x[q * 3 + 0], qy = x[q * 3 + 1], qz = x[q * 3 + 2];
    const float* cr = x + (size_t)(b * NN + cand) * 3;
    float d = qx * cr[0] + qy * cr[1] + qz * cr[2];
    dist[(size_t)q * NN + cand] = 2.f * d - sq[b * NN + cand];
}

// ---------------- stages 2-4 distances: GEMM-style, ld=512 ----------------
template<int C>
__global__ __launch_bounds__(256) void dist_k(const float* __restrict__ xt, int off,
                                              const float* __restrict__ sq,
                                              float* __restrict__ dist) {
    int b    = blockIdx.x >> 7;
    int tile = (blockIdx.x >> 3) & 15;
    int qs   = blockIdx.x & 7;
    int lane = threadIdx.x & 63;
    int wv   = __builtin_amdgcn_readfirstlane(threadIdx.x >> 6);
    int cand = tile * 64 + lane;
    float4 row[C / 4];
    const float* rp = xt + (size_t)(b * NN + cand) * LDC + off;
#pragma unroll
    for (int i = 0; i < C / 4; i++) row[i] = *(const float4*)(rp + 4 * i);
    float sqc = sq[b * NN + cand];
    for (int qg = qs * 8 + wv; qg < qs * 8 + 8; qg += 4) {
        int q0 = qg * 16;
        float acc[16];
#pragma unroll
        for (int i = 0; i < 16; i++) acc[i] = 0.f;
        const float* qbase = xt + (size_t)(b * NN + q0) * LDC + off;
#pragma unroll 2
        for (int c4 = 0; c4 < C / 4; c4++) {
            float4 rv = row[c4];
#pragma unroll
            for (int i = 0; i < 16; i++) {
                float4 qv = *(const float4*)(qbase + (size_t)i * LDC + 4 * c4);
                acc[i] += rv.x * qv.x + rv.y * qv.y + rv.z * qv.z + rv.w * qv.w;
            }
        }
#pragma unroll
        for (int i = 0; i < 16; i++)
            dist[(size_t)(b * NN + q0 + i) * NN + cand] = 2.f * acc[i] - sqc;
    }
}

// ---------------- top-20 selection: one wave per query, no barriers ----------------
__global__ __launch_bounds__(256) void select_k(const float* __restrict__ dist,
                                                int* __restrict__ idxout) {
    int q = blockIdx.x * 4 + (threadIdx.x >> 6);
    int lane = threadIdx.x & 63;
    const float* dq = dist + (size_t)q * NN;
    float d[16];
#pragma unroll
    for (int j = 0; j < 16; j++) d[j] = dq[lane + 64 * j];
    for (int t = 0; t < KNNK; t++) {
        float bv = d[0]; int bj = 0;
#pragma unroll
        for (int j = 1; j < 16; j++) if (d[j] > bv) { bv = d[j]; bj = j; }
        int bm = bj * 64 + lane;
        for (int s = 1; s < 64; s <<= 1) {
            float ov = __shfl_xor(bv, s);
            int   om = __shfl_xor(bm, s);
            if (ov > bv || (ov == bv && om < bm)) { bv = ov; bm = om; }
        }
        if (lane == 0) idxout[q * KNNK + t] = bm;
        if ((bm & 63) == lane) {
            int slot = bm >> 6;
#pragma unroll
            for (int j = 0; j < 16; j++) if (j == slot) d[j] = -INFINITY;
        }
    }
}

// ---------------- stage-1 z-gemm (C=3) ----------------
__global__ __launch_bounds__(256) void zgemm3_k(const float* __restrict__ x, const float* __restrict__ w1,
                                                float* __restrict__ zf) {
    int i = blockIdx.x * 256 + threadIdx.x;
    int n = i >> 7, j = i & 127;
    const float* wr = w1 + (j < 64 ? j * 6 : (j - 64) * 6 + 3);
    const float* xr = x + n * 3;
    zf[(size_t)n * 128 + j] = wr[0] * xr[0] + wr[1] * xr[1] + wr[2] * xr[2];
}

// ---------------- z-gemm: zf[n][j] = (j<O ? Wa_j : Wb_{j-O}) . x[n] ----------------
// For O2=512: each thread fuses j and j+256 (Wa row tid and Wb row tid) -> half the ds_reads.
template<int C, int O2>
__global__ __launch_bounds__(256) void zgemm_k(const float* __restrict__ xt, int off,
                                               const float* __restrict__ w,
                                               float* __restrict__ zf) {
    constexpr int O = O2 / 2;
    __shared__ __align__(16) float xs[16][C];
    int p0 = blockIdx.x * 16;
    int tid = threadIdx.x;
    for (int j = tid; j < 16 * (C / 4); j += 256) {
        int p = j / (C / 4), c4 = j % (C / 4);
        *(float4*)&xs[p][4 * c4] = *(const float4*)(xt + (size_t)(p0 + p) * LDC + off + 4 * c4);
    }
    __syncthreads();
    if constexpr (O2 > 256) {
        const float* wr0 = w + (size_t)tid * 2 * C;        // Wa row tid  -> col tid
        const float* wr1 = wr0 + C;                        // Wb row tid  -> col 256+tid
        float acc0[16], acc1[16];
#pragma unroll
        for (int p = 0; p < 16; p++) { acc0[p] = 0.f; acc1[p] = 0.f; }
        for (int c4 = 0; c4 < C / 4; c4++) {
            float4 w0 = *(const float4*)(wr0 + 4 * c4);
            float4 w1v = *(const float4*)(wr1 + 4 * c4);
#pragma unroll
            for (int p = 0; p < 16; p++) {
                float4 xv = *(const float4*)&xs[p][4 * c4];
                acc0[p] += w0.x * xv.x + w0.y * xv.y + w0.z * xv.z + w0.w * xv.w;
                acc1[p] += w1v.x * xv.x + w1v.y * xv.y + w1v.z * xv.z + w1v.w * xv.w;
            }
        }
#pragma unroll
        for (int p = 0; p < 16; p++) {
            zf[(size_t)(p0 + p) * O2 + tid]       = acc0[p];
            zf[(size_t)(p0 + p) * O2 + 256 + tid] = acc1[p];
        }
    } else {
        for (int j = tid; j < O2; j += 256) {
            const float* wr = w + (j < O ? (size_t)j * 2 * C : (size_t)(j - O) * 2 * C + C);
            float acc[16];
#pragma unroll
            for (int p = 0; p < 16; p++) acc[p] = 0.f;
            for (int c4 = 0; c4 < C / 4; c4++) {
                float4 wv = *(const float4*)(wr + 4 * c4);
#pragma unroll
                for (int p = 0; p < 16; p++) {
                    float4 xv = *(const float4*)&xs[p][4 * c4];
                    acc[p] += wv.x * xv.x + wv.y * xv.y + wv.z * xv.z + wv.w * xv.w;
                }
            }
#pragma unroll
            for (int p = 0; p < 16; p++) zf[(size_t)(p0 + p) * O2 + j] = acc[p];
        }
    }
}

// ---------------- gather + stats ----------------
template<int O2>
__global__ __launch_bounds__(256) void gatherstats_k(const float* __restrict__ zf,
                                                     const int* __restrict__ idx,
                                                     float* __restrict__ ymax, float* __restrict__ ymin,
                                                     float* __restrict__ psum, float* __restrict__ psumsq) {
    constexpr int O = O2 / 2;
    int wv = threadIdx.x >> 6, lane = threadIdx.x & 63;
    int n = blockIdx.x * 4 + wv;
    int b = n >> 10;
    const float* zbatch = zf + (size_t)b * NN * O2;
    int nb[KNNK];
#pragma unroll
    for (int k = 0; k < KNNK; k++) nb[k] = idx[n * KNNK + k];
#pragma unroll
    for (int ch = 0; ch < O / 64; ch++) {
        int o = ch * 64 + lane;
        float g[KNNK];
#pragma unroll
        for (int k = 0; k < KNNK; k++) g[k] = zbatch[(size_t)nb[k] * O2 + o];
        float mx = -INFINITY, mn = INFINITY, s = 0.f, ss = 0.f;
#pragma unroll
        for (int k = 0; k < KNNK; k++) {
            float v = g[k];
            mx = fmaxf(mx, v); mn = fminf(mn, v); s += v; ss += v * v;
        }
        float zn  = zf[(size_t)n * O2 + o];
        float zbn = zf[(size_t)n * O2 + O + o];
        float d = zbn - zn;
        mx += d; mn += d;
        ss = ss + 2.f * d * s + (float)KNNK * d * d;
        s  = s + (float)KNNK * d;
        ymax  [(size_t)n * O + o] = mx;
        ymin  [(size_t)n * O + o] = mn;
        psum  [(size_t)n * O + o] = s;
        psumsq[(size_t)n * O + o] = ss;
    }
}

// ---------------- BN reduce pass 1 ----------------
__global__ __launch_bounds__(256) void bnred1_k(const float* __restrict__ pn, const float* __restrict__ pq,
                                                int O, float* __restrict__ r1s, float* __restrict__ r1q) {
    __shared__ float ls[4][64], lq[4][64];
    int lane = threadIdx.x & 63, wv = threadIdx.x >> 6;
    int o = blockIdx.x * 64 + lane;
    int n0 = blockIdx.y * 256;
    float s = 0.f, q = 0.f;
    for (int r = wv; r < 256; r += 4) {
        s += pn[(size_t)(n0 + r) * O + o];
        q += pq[(size_t)(n0 + r) * O + o];
    }
    ls[wv][lane] = s; lq[wv][lane] = q;
    __syncthreads();
    if (wv == 0) {
        s = ls[0][lane] + ls[1][lane] + ls[2][lane] + ls[3][lane];
        q = lq[0][lane] + lq[1][lane] + lq[2][lane] + lq[3][lane];
        r1s[(size_t)blockIdx.y * O + o] = s;
        r1q[(size_t)blockIdx.y * O + o] = q;
    }
}

// ---------------- BN reduce pass 2 + scale/shift ----------------
__global__ __launch_bounds__(64) void bnred2_k(const float* __restrict__ r1s, const float* __restrict__ r1q,
                                               const float* __restrict__ g, const float* __restrict__ beta,
                                               int O, double invM,
                                               float* __restrict__ s_out, float* __restrict__ t_out) {
    int o = blockIdx.x, lane = threadIdx.x;
    double s = 0.0, q = 0.0;
    if (lane < 32) { s = r1s[(size_t)lane * O + o]; q = r1q[(size_t)lane * O + o]; }
#pragma unroll
    for (int m = 1; m < 32; m <<= 1) { s += __shfl_xor(s, m); q += __shfl_xor(q, m); }
    if (lane == 0) {
        double mean = s * invM;
        double var = q * invM - mean * mean;
        float inv = (float)(1.0 / sqrt(var + 1e-5));
        float sc = g[o] * inv;
        s_out[o] = sc;
        t_out[o] = beta[o] - (float)mean * sc;
    }
}

// ---------------- BN+lrelu on max/min (monotone), write into cat buffer ----------------
template<int O>
__global__ void epilogue_k(const float* __restrict__ ymax, const float* __restrict__ ymin,
                           const float* __restrict__ s, const float* __restrict__ t,
                           float* __restrict__ xtcat, int off_out) {
    int i = blockIdx.x * blockDim.x + threadIdx.x;
    if (i >= BB * NN * O) return;
    int bn = i / O;
    int o = i & (O - 1);
    float sc = s[o];
    float v = sc >= 0.f ? ymax[i] : ymin[i];
    float y = sc * v + t[o];
    y = y >= 0.f ? y : 0.2f * y;
    xtcat[(size_t)bn * LDC + off_out + o] = y;
}

// ---------------- stage 5: bf16 MFMA GEMM w/ fused per-16-row stats ----------------
// grid = 64 Mtiles x 4 Ntiles; block 256 = 4 waves (2x2); tile 128x128, K=512 (8 chunks of 64)
__global__ __launch_bounds__(256) void gemm5_mfma(const __hip_bfloat16* __restrict__ xbf,
                                                  const __hip_bfloat16* __restrict__ wbf,
                                                  float* __restrict__ pmax, float* __restrict__ pmn,
                                                  float* __restrict__ ps, float* __restrict__ pq) {
    __shared__ __hip_bfloat16 A[128][72];
    __shared__ __hip_bfloat16 W[128][72];
    int mt = blockIdx.x >> 2, nt = blockIdx.x & 3;
    int tid = threadIdx.x;
    int lane = tid & 63, wvx = tid >> 6;
    int mw = wvx >> 1, nw = wvx & 1;
    int m0 = lane & 15, qd = lane >> 4;
    int r = tid & 127, hf = tid >> 7;
    facc4 acc[4][4];
    facc4 zz = {0.f, 0.f, 0.f, 0.f};
#pragma unroll
    for (int mi = 0; mi < 4; mi++)
#pragma unroll
        for (int ni = 0; ni < 4; ni++) acc[mi][ni] = zz;
    for (int kc = 0; kc < 8; kc++) {
        const __hip_bfloat16* ap = xbf + (size_t)(mt * 128 + r) * 512 + kc * 64 + hf * 32;
        const __hip_bfloat16* wp = wbf + (size_t)(nt * 128 + r) * 512 + kc * 64 + hf * 32;
#pragma unroll
        for (int u = 0; u < 4; u++) {
            bh8 av = *(const bh8*)(ap + 8 * u);
            bh8 wv = *(const bh8*)(wp + 8 * u);
            *(bh8*)&A[r][hf * 32 + 8 * u] = av;
            *(bh8*)&W[r][hf * 32 + 8 * u] = wv;
        }
        __syncthreads();
#pragma unroll
        for (int kk = 0; kk < 2; kk++) {
            bfrag8 af[4], bf[4];
#pragma unroll
            for (int mi = 0; mi < 4; mi++)
                af[mi] = *(const bfrag8*)&A[64 * mw + 16 * mi + m0][32 * kk + 8 * qd];
#pragma unroll
            for (int ni = 0; ni < 4; ni++)
                bf[ni] = *(const bfrag8*)&W[64 * nw + 16 * ni + m0][32 * kk + 8 * qd];
#pragma unroll
            for (int mi = 0; mi < 4; mi++)
#pragma unroll
                for (int ni = 0; ni < 4; ni++)
                    acc[mi][ni] = __builtin_amdgcn_mfma_f32_16x16x32_bf16(af[mi], bf[ni], acc[mi][ni], 0, 0, 0);
        }
        __syncthreads();
    }
    // stats epilogue: rows of a 16-row group live in one wave (qd*4+rg within 16mi block)
#pragma unroll
    for (int mi = 0; mi < 4; mi++) {
        int grp = mt * 8 + mw * 4 + mi;      // 16-row group id in [0,512)
#pragma unroll
        for (int ni = 0; ni < 4; ni++) {
            float mx = -INFINITY, mn = INFINITY, s = 0.f, ss = 0.f;
#pragma unroll
            for (int rg = 0; rg < 4; rg++) {
                float v = acc[mi][ni][rg];
                mx = fmaxf(mx, v); mn = fminf(mn, v); s += v; ss += v * v;
            }
#pragma unroll
            for (int m = 16; m < 64; m <<= 1) {
                mx = fmaxf(mx, __shfl_xor(mx, m));
                mn = fminf(mn, __shfl_xor(mn, m));
                s += __shfl_xor(s, m);
                ss += __shfl_xor(ss, m);
            }
            if (qd == 0) {
                int o = nt * 128 + nw * 64 + ni * 16 + m0;
                pmax[(size_t)grp * 512 + o] = mx;
                pmn [(size_t)grp * 512 + o] = mn;
                ps  [(size_t)grp * 512 + o] = s;
                pq  [(size_t)grp * 512 + o] = ss;
            }
        }
    }
}

// ---------------- stage-5 BN stats from the 512 per-group partials ----------------
__global__ __launch_bounds__(256) void bnstat5_k(const float* __restrict__ ps, const float* __restrict__ pq,
                                                 const float* __restrict__ g, const float* __restrict__ beta,
                                                 float* __restrict__ s_out, float* __restrict__ t_out) {
    __shared__ double lds_s[4][64], lds_q[4][64];
    int lane = threadIdx.x & 63, wv = threadIdx.x >> 6;
    int o = blockIdx.x * 64 + lane;
    double s = 0.0, q = 0.0;
    for (int r = wv; r < 512; r += 4) {
        s += ps[(size_t)r * 512 + o];
        q += pq[(size_t)r * 512 + o];
    }
    lds_s[wv][lane] = s; lds_q[wv][lane] = q;
    __syncthreads();
    if (wv == 0) {
        s = lds_s[0][lane] + lds_s[1][lane] + lds_s[2][lane] + lds_s[3][lane];
        q = lds_q[0][lane] + lds_q[1][lane] + lds_q[2][lane] + lds_q[3][lane];
        double invM = 1.0 / (BB * NN);
        double mean = s * invM;
        double var = q * invM - mean * mean;
        float inv = (float)(1.0 / sqrt(var + 1e-5));
        float sc = g[o] * inv;
        s_out[o] = sc;
        t_out[o] = beta[o] - (float)mean * sc;
    }
}

// ---------------- per-batch max/min reduce + BN + lrelu + feat @ wemb^T ----------------
__global__ __launch_bounds__(256) void featgemm_k(const float* __restrict__ pmax, const float* __restrict__ pmn,
                                                  const float* __restrict__ s, const float* __restrict__ t,
                                                  const float* __restrict__ wemb, float* __restrict__ out) {
    __shared__ __align__(16) float feat[512];
    int b = blockIdx.x, tid = threadIdx.x;
    for (int o = tid; o < 512; o += 256) {
        float mx = -INFINITY, mn = INFINITY;
        for (int r = b * 64; r < (b + 1) * 64; r++) {
            mx = fmaxf(mx, pmax[(size_t)r * 512 + o]);
            mn = fminf(mn, pmn [(size_t)r * 512 + o]);
        }
        float sc = s[o];
        float v = sc >= 0.f ? mx : mn;
        float y = sc * v + t[o];
        feat[o] = y >= 0.f ? y : 0.2f * y;
    }
    __syncthreads();
    const float4* wr = (const float4*)(wemb + (size_t)tid * 512);
    float acc = 0.f;
    for (int c4 = 0; c4 < 128; c4++) {
        float4 wv = wr[c4];
        float4 fv = *(const float4*)&feat[c4 * 4];
        acc += wv.x * fv.x + wv.y * fv.y + wv.z * fv.z + wv.w * fv.w;
    }
    out[(size_t)b * 256 + tid] = acc;
}

extern "C" void kernel_launch(void* const* d_in, const int* in_sizes, int n_in,
                              void* d_out, int out_size, void* d_ws, size_t ws_size,
                              hipStream_t stream) {
    const float* x    = (const float*)d_in[0];
    const float* w1   = (const float*)d_in[1];
    const float* g1   = (const float*)d_in[2];
    const float* b1   = (const float*)d_in[3];
    const float* w2   = (const float*)d_in[4];
    const float* g2   = (const float*)d_in[5];
    const float* b2   = (const float*)d_in[6];
    const float* w3   = (const float*)d_in[7];
    const float* g3   = (const float*)d_in[8];
    const float* b3   = (const float*)d_in[9];
    const float* w4   = (const float*)d_in[10];
    const float* g4   = (const float*)d_in[11];
    const float* b4   = (const float*)d_in[12];
    const float* w5   = (const float*)d_in[13];
    const float* g5   = (const float*)d_in[14];
    const float* b5   = (const float*)d_in[15];
    const float* wemb = (const float*)d_in[16];
    float* out = (float*)d_out;

    float* fws    = (float*)d_ws;
    float* xtcat  = fws;                                 // 4,194,304
    float* ymax   = xtcat + (size_t)BB * NN * 512;       // 2,097,152
    float* ymin   = ymax + (size_t)BB * NN * 256;        // 2,097,152
    float* psum   = ymin + (size_t)BB * NN * 256;        // 2,097,152
    float* psumsq = psum + (size_t)BB * NN * 256;        // 2,097,152
    float* distb  = ymax;                                // alias (dead before gatherstats)
    float* pmax   = ymax;                                // alias: stage-5 partials, 512*512 each
    float* pmn    = pmax + 512 * 512;
    float* ps5    = pmn + 512 * 512;
    float* pq5    = ps5 + 512 * 512;
    float* sqn    = psumsq + (size_t)BB * NN * 256;      // 8192
    float* s_arr  = sqn + BB * NN;                       // 512
    float* t_arr  = s_arr + 512;                         // 512
    float* r1s    = t_arr + 512;                         // 32*512
    float* r1q    = r1s + 32 * 512;                      // 32*512
    int*   idxb   = (int*)(r1q + 32 * 512);              // 8192*20 ints
    float* zfull  = (float*)(idxb + BB * NN * KNNK);     // 8192*512
    __hip_bfloat16* xbf  = (__hip_bfloat16*)(zfull + (size_t)BB * NN * 512);  // 8192*512 bf16
    __hip_bfloat16* w5bf = xbf + (size_t)BB * NN * 512;                       // 512*512 bf16

    const double invM_edge = 1.0 / ((double)BB * NN * KNNK);
    const int nbn = BB * NN;

    // ---- Stage 1: in = x (B,N,3), out ch [0,64) ----
    sqnorm_k<<<(nbn + 255) / 256, 256, 0, stream>>>(x, 3, 0, 3, sqn);
    dist3_k<<<dim3(nbn, 4), 256, 0, stream>>>(x, sqn, distb);
    select_k<<<nbn / 4, 256, 0, stream>>>(distb, idxb);
    zgemm3_k<<<nbn * 128 / 256, 256, 0, stream>>>(x, w1, zfull);
    gatherstats_k<128><<<nbn / 4, 256, 0, stream>>>(zfull, idxb, ymax, ymin, psum, psumsq);
    bnred1_k<<<dim3(1, 32), 256, 0, stream>>>(psum, psumsq, 64, r1s, r1q);
    bnred2_k<<<64, 64, 0, stream>>>(r1s, r1q, g1, b1, 64, invM_edge, s_arr, t_arr);
    epilogue_k<64><<<(nbn * 64 + 255) / 256, 256, 0, stream>>>(ymax, ymin, s_arr, t_arr, xtcat, 0);

    // ---- Stage 2: in ch [0,64), out [64,128) ----
    sqnorm_k<<<(nbn + 255) / 256, 256, 0, stream>>>(xtcat, 512, 0, 64, sqn);
    dist_k<64><<<1024, 256, 0, stream>>>(xtcat, 0, sqn, distb);
    select_k<<<nbn / 4, 256, 0, stream>>>(distb, idxb);
    zgemm_k<64, 128><<<nbn / 16, 256, 0, stream>>>(xtcat, 0, w2, zfull);
    gatherstats_k<128><<<nbn / 4, 256, 0, stream>>>(zfull, idxb, ymax, ymin, psum, psumsq);
    bnred1_k<<<dim3(1, 32), 256, 0, stream>>>(psum, psumsq, 64, r1s, r1q);
    bnred2_k<<<64, 64, 0, stream>>>(r1s, r1q, g2, b2, 64, invM_edge, s_arr, t_arr);
    epilogue_k<64><<<(nbn * 64 + 255) / 256, 256, 0, stream>>>(ymax, ymin, s_arr, t_arr, xtcat, 64);

    // ---- Stage 3: in ch [64,128), out [128,256) ----
    sqnorm_k<<<(nbn + 255) / 256, 256, 0, stream>>>(xtcat, 512, 64, 64, sqn);
    dist_k<64><<<1024, 256, 0, stream>>>(xtcat, 64, sqn, distb);
    select_k<<<nbn / 4, 256, 0, stream>>>(distb, idxb);
    zgemm_k<64, 256><<<nbn / 16, 256, 0, stream>>>(xtcat, 64, w3, zfull);
    gatherstats_k<256><<<nbn / 4, 256, 0, stream>>>(zfull, idxb, ymax, ymin, psum, psumsq);
    bnred1_k<<<dim3(2, 32), 256, 0, stream>>>(psum, psumsq, 128, r1s, r1q);
    bnred2_k<<<128, 64, 0, stream>>>(r1s, r1q, g3, b3, 128, invM_edge, s_arr, t_arr);
    epilogue_k<128><<<(nbn * 128 + 255) / 256, 256, 0, stream>>>(ymax, ymin, s_arr, t_arr, xtcat, 128);

    // ---- Stage 4: in ch [128,256), out [256,512) ----
    sqnorm_k<<<(nbn + 255) / 256, 256, 0, stream>>>(xtcat, 512, 128, 128, sqn);
    dist_k<128><<<1024, 256, 0, stream>>>(xtcat, 128, sqn, distb);
    select_k<<<nbn / 4, 256, 0, stream>>>(distb, idxb);
    zgemm_k<128, 512><<<nbn / 16, 256, 0, stream>>>(xtcat, 128, w4, zfull);
    gatherstats_k<512><<<nbn / 4, 256, 0, stream>>>(zfull, idxb, ymax, ymin, psum, psumsq);
    bnred1_k<<<dim3(4, 32), 256, 0, stream>>>(psum, psumsq, 256, r1s, r1q);
    bnred2_k<<<256, 64, 0, stream>>>(r1s, r1q, g4, b4, 256, invM_edge, s_arr, t_arr);
    epilogue_k<256><<<(nbn * 256 + 255) / 256, 256, 0, stream>>>(ymax, ymin, s_arr, t_arr, xtcat, 256);

    // ---- Stage 5: bf16 converts, MFMA GEMM+stats, tiny reductions ----
    f2bf_k<<<512 * 512 / (256 * 8), 256, 0, stream>>>(w5, w5bf, 512 * 512);
    f2bf_k<<<nbn * 512 / (256 * 8), 256, 0, stream>>>(xtcat, xbf, nbn * 512);
    gemm5_mfma<<<256, 256, 0, stream>>>(xbf, w5bf, pmax, pmn, ps5, pq5);
    bnstat5_k<<<8, 256, 0, stream>>>(ps5, pq5, g5, b5, s_arr, t_arr);
    featgemm_k<<<BB, 256, 0, stream>>>(pmax, pmn, s_arr, t_arr, wemb, out);
}